// Round 1
// baseline (1106.416 us; speedup 1.0000x reference)
//
#include <hip/hip_runtime.h>
#include <math.h>

#define NEG_SLOPE 0.2f

__device__ __forceinline__ float leaky(float v) { return v >= 0.f ? v : NEG_SLOPE * v; }

// ---------------- edge dtype detect + convert ----------------
// If edge_index is int64 (little-endian, values < 2^31), every odd 32-bit word
// is zero. If int32, odd words are random node ids (P(zero)=1e-5 each).
__global__ void detect_kernel(const unsigned* __restrict__ w, int* __restrict__ flag)
{
    __shared__ int anynz;
    if (threadIdx.x == 0) anynz = 0;
    __syncthreads();
    bool nz = false;
#pragma unroll
    for (int j = 0; j < 8; ++j) {
        int idx = 2 * (threadIdx.x + 256 * j) + 1;   // max 4095 < 3.2M words
        nz |= (w[idx] != 0u);
    }
    if (nz) anynz = 1;
    __syncthreads();
    if (threadIdx.x == 0) *flag = anynz ? 0 : 1;     // 1 => int64 layout
}

__global__ void convert_kernel(const unsigned* __restrict__ w, int* __restrict__ out,
                               const int* __restrict__ flag, int n)
{
    int id = blockIdx.x * 256 + threadIdx.x;
    if (id >= n) return;
    int f = *flag;
    out[id] = (int)(f ? w[2 * id] : w[id]);
}

// ---------------- GEMM1: h1 = x @ W1, fused per-head attention logits ----------------
__global__ __launch_bounds__(256) void gemm1_kernel(
    const float* __restrict__ x, const float* __restrict__ W,
    const float* __restrict__ as1, const float* __restrict__ ad1,
    float* __restrict__ h1, float* __restrict__ als, float* __restrict__ ald, int N)
{
    __shared__ float xs[32][64];
    __shared__ float ws[64][68];   // pad 68 for conflict-free float4 staging
    const int t = threadIdx.x;
    const int c = t & 63;          // output column 0..63
    const int wv = t >> 6;         // wave id 0..3 -> row group
    const int row0 = blockIdx.x * 32;

    float acc[8];
#pragma unroll
    for (int i = 0; i < 8; ++i) acc[i] = 0.f;

    for (int kc = 0; kc < 4; ++kc) {
#pragma unroll
        for (int j = 0; j < 2; ++j) {
            int id = t + 256 * j;
            int r = id >> 4, k4 = id & 15;
            int row = row0 + r;
            float4 v = make_float4(0.f, 0.f, 0.f, 0.f);
            if (row < N) v = *(const float4*)(x + (size_t)row * 256 + kc * 64 + k4 * 4);
            *(float4*)(&xs[r][k4 * 4]) = v;
        }
#pragma unroll
        for (int j = 0; j < 4; ++j) {
            int id = t + 256 * j;
            int k = id >> 4, c4 = id & 15;
            float4 v = *(const float4*)(W + (size_t)(kc * 64 + k) * 64 + c4 * 4);
            *(float4*)(&ws[k][c4 * 4]) = v;
        }
        __syncthreads();
#pragma unroll
        for (int k = 0; k < 64; ++k) {
            float w = ws[k][c];
#pragma unroll
            for (int r8 = 0; r8 < 8; ++r8)
                acc[r8] += xs[wv * 8 + r8][k] * w;
        }
        __syncthreads();
    }

    // epilogue: store h1 + fused attention logits (reduce over 8 channels/head)
    float a_s = as1[c], a_d = ad1[c];   // att arrays are [8][8] flattened = index c
#pragma unroll
    for (int r8 = 0; r8 < 8; ++r8) {
        int row = row0 + wv * 8 + r8;
        if (row < N) h1[(size_t)row * 64 + c] = acc[r8];
        float vs = acc[r8] * a_s, vd = acc[r8] * a_d;
#pragma unroll
        for (int off = 1; off < 8; off <<= 1) {
            vs += __shfl_xor(vs, off);
            vd += __shfl_xor(vd, off);
        }
        if ((c & 7) == 0 && row < N) {
            als[row * 8 + (c >> 3)] = vs;
            ald[row * 8 + (c >> 3)] = vd;
        }
    }
}

// ---------------- GEMM2: h2 = x2 @ W2, fused single-head logits ----------------
__global__ __launch_bounds__(256) void gemm2_kernel(
    const float* __restrict__ x2, const float* __restrict__ W2,
    const float* __restrict__ as2, const float* __restrict__ ad2,
    float* __restrict__ h2, float* __restrict__ al2s, float* __restrict__ al2d, int N)
{
    __shared__ float xs[32][64];
    __shared__ float ws[64][40];
    const int t = threadIdx.x;
    const int c = t & 63;
    const int wv = t >> 6;
    const int row0 = blockIdx.x * 32;

#pragma unroll
    for (int j = 0; j < 2; ++j) {
        int id = t + 256 * j;
        int r = id >> 4, k4 = id & 15;
        int row = row0 + r;
        float4 v = make_float4(0.f, 0.f, 0.f, 0.f);
        if (row < N) v = *(const float4*)(x2 + (size_t)row * 64 + k4 * 4);
        *(float4*)(&xs[r][k4 * 4]) = v;
    }
    for (int id = t; id < 64 * 40; id += 256) ws[id / 40][id % 40] = W2[id];
    __syncthreads();

    const int cc = c < 40 ? c : 0;
    float acc[8];
#pragma unroll
    for (int i = 0; i < 8; ++i) acc[i] = 0.f;
#pragma unroll
    for (int k = 0; k < 64; ++k) {
        float w = ws[k][cc];
#pragma unroll
        for (int r8 = 0; r8 < 8; ++r8)
            acc[r8] += xs[wv * 8 + r8][k] * w;
    }

    float a_s = as2[cc], a_d = ad2[cc];
#pragma unroll
    for (int r8 = 0; r8 < 8; ++r8) {
        int row = row0 + wv * 8 + r8;
        if (row < N && c < 40) h2[(size_t)row * 40 + c] = acc[r8];
        float vs = (c < 40) ? acc[r8] * a_s : 0.f;
        float vd = (c < 40) ? acc[r8] * a_d : 0.f;
#pragma unroll
        for (int off = 1; off < 64; off <<= 1) {
            vs += __shfl_xor(vs, off);
            vd += __shfl_xor(vd, off);
        }
        if (c == 0 && row < N) { al2s[row] = vs; al2d[row] = vd; }
    }
}

// ---------------- layer 1 attention / aggregation ----------------
__global__ void init1_kernel(const float* __restrict__ als, const float* __restrict__ ald,
                             float* __restrict__ den, int NH)
{
    int id = blockIdx.x * 256 + threadIdx.x;
    if (id >= NH) return;
    den[id] = __expf(leaky(als[id] + ald[id]));   // self-loop term
}

__global__ void edgeA1_kernel(const int* __restrict__ eg, const float* __restrict__ als,
                              const float* __restrict__ ald, float* __restrict__ den, int E)
{
    int id = blockIdx.x * 256 + threadIdx.x;
    if (id >= E * 8) return;
    int e = id >> 3, h = id & 7;
    int src = eg[e], dst = eg[E + e];
    float p = __expf(leaky(als[src * 8 + h] + ald[dst * 8 + h]));
    atomicAdd(&den[dst * 8 + h], p);
}

__global__ void x2init_kernel(const float* __restrict__ h1, const float* __restrict__ als,
                              const float* __restrict__ ald, const float* __restrict__ den,
                              float* __restrict__ x2, int N64)
{
    int id = blockIdx.x * 256 + threadIdx.x;
    if (id >= N64) return;
    int n = id >> 6, c = id & 63, h = c >> 3;
    float p = __expf(leaky(als[n * 8 + h] + ald[n * 8 + h]));
    x2[id] = h1[id] * (p / den[n * 8 + h]);
}

__global__ void edgeB1_kernel(const int* __restrict__ eg, const float* __restrict__ h1,
                              const float* __restrict__ als, const float* __restrict__ ald,
                              const float* __restrict__ den, float* __restrict__ x2, int E)
{
    int id = blockIdx.x * 256 + threadIdx.x;
    if (id >= E * 64) return;
    int e = id >> 6, c = id & 63, h = c >> 3;
    int src = eg[e], dst = eg[E + e];
    float v = leaky(als[src * 8 + h] + ald[dst * 8 + h]);
    float alpha = __expf(v) / den[dst * 8 + h];
    atomicAdd(&x2[dst * 64 + c], h1[src * 64 + c] * alpha);
}

__global__ void elu_kernel(float* __restrict__ x2, const float* __restrict__ b1, int N64)
{
    int id = blockIdx.x * 256 + threadIdx.x;
    if (id >= N64) return;
    float v = x2[id] + b1[id & 63];
    x2[id] = v > 0.f ? v : expm1f(v);
}

// ---------------- layer 2 attention / aggregation ----------------
__global__ void init2_kernel(const float* __restrict__ s, const float* __restrict__ d,
                             float* __restrict__ den, int N)
{
    int id = blockIdx.x * 256 + threadIdx.x;
    if (id >= N) return;
    den[id] = __expf(leaky(s[id] + d[id]));
}

__global__ void edgeA2_kernel(const int* __restrict__ eg, const float* __restrict__ s,
                              const float* __restrict__ d, float* __restrict__ den, int E)
{
    int id = blockIdx.x * 256 + threadIdx.x;
    if (id >= E) return;
    int src = eg[id], dst = eg[E + id];
    atomicAdd(&den[dst], __expf(leaky(s[src] + d[dst])));
}

__global__ void outinit2_kernel(const float* __restrict__ h2, const float* __restrict__ s,
                                const float* __restrict__ d, const float* __restrict__ den,
                                float* __restrict__ out, int N40)
{
    int id = blockIdx.x * 256 + threadIdx.x;
    if (id >= N40) return;
    int n = id / 40;
    float p = __expf(leaky(s[n] + d[n]));
    out[id] = h2[id] * (p / den[n]);
}

__global__ void edgeB2_kernel(const int* __restrict__ eg, const float* __restrict__ h2,
                              const float* __restrict__ s, const float* __restrict__ d,
                              const float* __restrict__ den, float* __restrict__ out, int E)
{
    int id = blockIdx.x * 256 + threadIdx.x;
    if (id >= E * 40) return;
    int e = id / 40, c = id - e * 40;
    int src = eg[e], dst = eg[E + e];
    float alpha = __expf(leaky(s[src] + d[dst])) / den[dst];
    atomicAdd(&out[dst * 40 + c], h2[src * 40 + c] * alpha);
}

// ---------------- final log-softmax over 40 classes ----------------
__global__ void logsoftmax_kernel(float* __restrict__ out, const float* __restrict__ b2, int N)
{
    int t = threadIdx.x, c = t & 63, wv = t >> 6;
    int row = blockIdx.x * 4 + wv;
    if (row >= N) return;
    float v = (c < 40) ? out[row * 40 + c] + b2[c] : -INFINITY;
    float m = v;
#pragma unroll
    for (int off = 1; off < 64; off <<= 1) m = fmaxf(m, __shfl_xor(m, off));
    float p = (c < 40) ? __expf(v - m) : 0.f;
    float sum = p;
#pragma unroll
    for (int off = 1; off < 64; off <<= 1) sum += __shfl_xor(sum, off);
    if (c < 40) out[row * 40 + c] = v - m - logf(sum);
}

extern "C" void kernel_launch(void* const* d_in, const int* in_sizes, int n_in,
                              void* d_out, int out_size, void* d_ws, size_t ws_size,
                              hipStream_t stream)
{
    const float*    x    = (const float*)d_in[0];
    const unsigned* eraw = (const unsigned*)d_in[1];
    const float*    W1   = (const float*)d_in[2];
    const float*    as1  = (const float*)d_in[3];
    const float*    ad1  = (const float*)d_in[4];
    const float*    b1   = (const float*)d_in[5];
    const float*    W2   = (const float*)d_in[6];
    const float*    as2  = (const float*)d_in[7];
    const float*    ad2  = (const float*)d_in[8];
    const float*    b2   = (const float*)d_in[9];
    float* out = (float*)d_out;

    const int N = in_sizes[0] / 256;
    const int E = in_sizes[1] / 2;

    char* ws = (char*)d_ws;
    size_t off = 0;
    auto alloc = [&](size_t bytes) {
        size_t o = off;
        off = (off + bytes + 255) & ~(size_t)255;
        return o;
    };
    int*   edges = (int*)  (ws + alloc((size_t)2 * E * 4));
    float* h1    = (float*)(ws + alloc((size_t)N * 64 * 4));   // reused as h2 in layer 2
    float* als1  = (float*)(ws + alloc((size_t)N * 8 * 4));
    float* ald1  = (float*)(ws + alloc((size_t)N * 8 * 4));
    float* den1  = (float*)(ws + alloc((size_t)N * 8 * 4));
    float* x2    = (float*)(ws + alloc((size_t)N * 64 * 4));
    float* al2s  = (float*)(ws + alloc((size_t)N * 4));
    float* al2d  = (float*)(ws + alloc((size_t)N * 4));
    float* den2  = (float*)(ws + alloc((size_t)N * 4));
    int*   flag  = (int*)  (ws + alloc(256));
    float* h2 = h1;

    dim3 B(256);
    detect_kernel<<<1, B, 0, stream>>>(eraw, flag);
    convert_kernel<<<dim3((2 * E + 255) / 256), B, 0, stream>>>(eraw, edges, flag, 2 * E);

    // layer 1
    gemm1_kernel<<<dim3((N + 31) / 32), B, 0, stream>>>(x, W1, as1, ad1, h1, als1, ald1, N);
    init1_kernel<<<dim3((N * 8 + 255) / 256), B, 0, stream>>>(als1, ald1, den1, N * 8);
    edgeA1_kernel<<<dim3((E * 8 + 255) / 256), B, 0, stream>>>(edges, als1, ald1, den1, E);
    x2init_kernel<<<dim3((N * 64 + 255) / 256), B, 0, stream>>>(h1, als1, ald1, den1, x2, N * 64);
    edgeB1_kernel<<<dim3((unsigned)(((long long)E * 64 + 255) / 256), 1, 1), B, 0, stream>>>(
        edges, h1, als1, ald1, den1, x2, E);
    elu_kernel<<<dim3((N * 64 + 255) / 256), B, 0, stream>>>(x2, b1, N * 64);

    // layer 2
    gemm2_kernel<<<dim3((N + 31) / 32), B, 0, stream>>>(x2, W2, as2, ad2, h2, al2s, al2d, N);
    init2_kernel<<<dim3((N + 255) / 256), B, 0, stream>>>(al2s, al2d, den2, N);
    edgeA2_kernel<<<dim3((E + 255) / 256), B, 0, stream>>>(edges, al2s, al2d, den2, E);
    outinit2_kernel<<<dim3((N * 40 + 255) / 256), B, 0, stream>>>(h2, al2s, al2d, den2, out, N * 40);
    edgeB2_kernel<<<dim3((unsigned)(((long long)E * 40 + 255) / 256), 1, 1), B, 0, stream>>>(
        edges, h2, al2s, al2d, den2, out, E);
    logsoftmax_kernel<<<dim3((N + 3) / 4), B, 0, stream>>>(out, b2, N);
}

// Round 2
// 799.521 us; speedup vs baseline: 1.3838x; 1.3838x over previous
//
#include <hip/hip_runtime.h>
#include <hip/hip_bf16.h>
#include <math.h>

#define NEG_SLOPE 0.2f
#define CHUNK 1024

__device__ __forceinline__ float leaky(float v) { return v >= 0.f ? v : NEG_SLOPE * v; }

// ---------------- edge dtype detect + convert ----------------
__global__ void detect_kernel(const unsigned* __restrict__ w, int* __restrict__ flag)
{
    __shared__ int anynz;
    if (threadIdx.x == 0) anynz = 0;
    __syncthreads();
    bool nz = false;
#pragma unroll
    for (int j = 0; j < 8; ++j) {
        int idx = 2 * (threadIdx.x + 256 * j) + 1;
        nz |= (w[idx] != 0u);
    }
    if (nz) anynz = 1;
    __syncthreads();
    if (threadIdx.x == 0) *flag = anynz ? 0 : 1;     // 1 => int64 layout
}

__global__ void convert_kernel(const unsigned* __restrict__ w, int* __restrict__ out,
                               const int* __restrict__ flag, int n)
{
    int id = blockIdx.x * 256 + threadIdx.x;
    if (id >= n) return;
    int f = *flag;
    out[id] = (int)(f ? w[2 * id] : w[id]);
}

// ---------------- CSR build (dst-sorted) ----------------
__global__ void zero2_kernel(int* __restrict__ deg, int* __restrict__ cur, int N)
{
    int id = blockIdx.x * 256 + threadIdx.x;
    if (id < N) { deg[id] = 0; cur[id] = 0; }
}

__global__ void hist_kernel(const int* __restrict__ eg, int* __restrict__ deg, int E)
{
    int e = blockIdx.x * 256 + threadIdx.x;
    if (e < E) atomicAdd(&deg[eg[E + e]], 1);
}

__global__ void chunksum_kernel(const int* __restrict__ deg, int* __restrict__ csum, int N)
{
    int b = blockIdx.x, t = threadIdx.x;
    int base = b * CHUNK + t * 4;
    int s = 0;
#pragma unroll
    for (int j = 0; j < 4; ++j) { int i = base + j; if (i < N) s += deg[i]; }
#pragma unroll
    for (int off = 1; off < 64; off <<= 1) s += __shfl_xor(s, off);
    __shared__ int wt[4];
    if ((t & 63) == 0) wt[t >> 6] = s;
    __syncthreads();
    if (t == 0) csum[b] = wt[0] + wt[1] + wt[2] + wt[3];
}

// single wave; NB <= 128
__global__ void chunkscan_kernel(const int* __restrict__ csum, int* __restrict__ coff,
                                 int* __restrict__ rowptrN, int NB, int E)
{
    int lane = threadIdx.x;
    int v0 = (lane < NB) ? csum[lane] : 0;
    int v1 = (lane + 64 < NB) ? csum[lane + 64] : 0;
    int s0 = v0;
#pragma unroll
    for (int off = 1; off < 64; off <<= 1) { int u = __shfl_up(s0, off); if (lane >= off) s0 += u; }
    int tot0 = __shfl(s0, 63);
    if (lane < NB) coff[lane] = s0 - v0;
    int s1 = v1;
#pragma unroll
    for (int off = 1; off < 64; off <<= 1) { int u = __shfl_up(s1, off); if (lane >= off) s1 += u; }
    if (lane + 64 < NB) coff[lane + 64] = tot0 + s1 - v1;
    if (lane == 0) *rowptrN = E;
}

__global__ void writeptr_kernel(const int* __restrict__ deg, const int* __restrict__ coff,
                                int* __restrict__ rowptr, int N)
{
    int b = blockIdx.x, t = threadIdx.x;
    int base = b * CHUNK + t * 4;
    int d[4]; int s = 0;
#pragma unroll
    for (int j = 0; j < 4; ++j) { int i = base + j; d[j] = (i < N) ? deg[i] : 0; s += d[j]; }
    int lane = t & 63, wv = t >> 6;
    int incl = s;
#pragma unroll
    for (int off = 1; off < 64; off <<= 1) { int u = __shfl_up(incl, off); if (lane >= off) incl += u; }
    __shared__ int wt[4];
    if (lane == 63) wt[wv] = incl;
    __syncthreads();
    int wbase = 0;
    for (int w = 0; w < wv; ++w) wbase += wt[w];
    int run = wbase + incl - s + coff[b];
#pragma unroll
    for (int j = 0; j < 4; ++j) { int i = base + j; if (i < N) rowptr[i] = run; run += d[j]; }
}

__global__ void scatter_kernel(const int* __restrict__ eg, const int* __restrict__ rowptr,
                               int* __restrict__ cur, int* __restrict__ ssorted, int E)
{
    int e = blockIdx.x * 256 + threadIdx.x;
    if (e >= E) return;
    int dst = eg[E + e];
    int k = atomicAdd(&cur[dst], 1);
    ssorted[rowptr[dst] + k] = eg[e];
}

// ---------------- GEMM1: h1 = x @ W1 (bf16 out), fused attention logits ----------------
__global__ __launch_bounds__(256) void gemm1_kernel(
    const float* __restrict__ x, const float* __restrict__ W,
    const float* __restrict__ as1, const float* __restrict__ ad1,
    __hip_bfloat16* __restrict__ h1b, float* __restrict__ als, float* __restrict__ ald, int N)
{
    __shared__ float xs[32][64];
    __shared__ float ws[64][68];
    const int t = threadIdx.x;
    const int c = t & 63;
    const int wv = t >> 6;
    const int row0 = blockIdx.x * 32;

    float acc[8];
#pragma unroll
    for (int i = 0; i < 8; ++i) acc[i] = 0.f;

    for (int kc = 0; kc < 4; ++kc) {
#pragma unroll
        for (int j = 0; j < 2; ++j) {
            int id = t + 256 * j;
            int r = id >> 4, k4 = id & 15;
            int row = row0 + r;
            float4 v = make_float4(0.f, 0.f, 0.f, 0.f);
            if (row < N) v = *(const float4*)(x + (size_t)row * 256 + kc * 64 + k4 * 4);
            *(float4*)(&xs[r][k4 * 4]) = v;
        }
#pragma unroll
        for (int j = 0; j < 4; ++j) {
            int id = t + 256 * j;
            int k = id >> 4, c4 = id & 15;
            float4 v = *(const float4*)(W + (size_t)(kc * 64 + k) * 64 + c4 * 4);
            *(float4*)(&ws[k][c4 * 4]) = v;
        }
        __syncthreads();
#pragma unroll
        for (int k = 0; k < 64; ++k) {
            float w = ws[k][c];
#pragma unroll
            for (int r8 = 0; r8 < 8; ++r8)
                acc[r8] += xs[wv * 8 + r8][k] * w;
        }
        __syncthreads();
    }

    float a_s = as1[c], a_d = ad1[c];
#pragma unroll
    for (int r8 = 0; r8 < 8; ++r8) {
        int row = row0 + wv * 8 + r8;
        if (row < N) h1b[(size_t)row * 64 + c] = __float2bfloat16(acc[r8]);
        float vs = acc[r8] * a_s, vd = acc[r8] * a_d;
#pragma unroll
        for (int off = 1; off < 8; off <<= 1) {
            vs += __shfl_xor(vs, off);
            vd += __shfl_xor(vd, off);
        }
        if ((c & 7) == 0 && row < N) {
            als[row * 8 + (c >> 3)] = vs;
            ald[row * 8 + (c >> 3)] = vd;
        }
    }
}

// ---------------- agg1: per-dst-node softmax + aggregate + bias + ELU ----------------
__global__ __launch_bounds__(256) void agg1_kernel(
    const int* __restrict__ rowptr, const int* __restrict__ srcs,
    const __hip_bfloat16* __restrict__ h1b,
    const float* __restrict__ als, const float* __restrict__ ald,
    const float* __restrict__ b1, float* __restrict__ x2, int N)
{
    int lane = threadIdx.x & 63, wv = threadIdx.x >> 6;
    int n = blockIdx.x * 4 + wv;
    if (n >= N) return;
    int hb = lane >> 3;                    // head for this channel
    float aldn = ald[n * 8 + hb];
    float alsn = als[n * 8 + hb];
    // self-loop
    float p = __expf(leaky(alsn + aldn));
    float den = p;
    float acc = p * __bfloat162float(h1b[(size_t)n * 64 + lane]);
    int beg = rowptr[n], end = rowptr[n + 1];
    for (int i = beg; i < end; ++i) {
        int s = srcs[i];                   // broadcast within wave
        float pe = __expf(leaky(als[s * 8 + hb] + aldn));
        den += pe;
        acc += pe * __bfloat162float(h1b[(size_t)s * 64 + lane]);
    }
    float v = acc / den + b1[lane];
    x2[(size_t)n * 64 + lane] = v > 0.f ? v : expm1f(v);
}

// ---------------- GEMM2: h2 = x2 @ W2 (bf16 out), fused single-head logits ----------------
__global__ __launch_bounds__(256) void gemm2_kernel(
    const float* __restrict__ x2, const float* __restrict__ W2,
    const float* __restrict__ as2, const float* __restrict__ ad2,
    __hip_bfloat16* __restrict__ h2b, float* __restrict__ al2s, float* __restrict__ al2d, int N)
{
    __shared__ float xs[32][64];
    __shared__ float ws[64][40];
    const int t = threadIdx.x;
    const int c = t & 63;
    const int wv = t >> 6;
    const int row0 = blockIdx.x * 32;

#pragma unroll
    for (int j = 0; j < 2; ++j) {
        int id = t + 256 * j;
        int r = id >> 4, k4 = id & 15;
        int row = row0 + r;
        float4 v = make_float4(0.f, 0.f, 0.f, 0.f);
        if (row < N) v = *(const float4*)(x2 + (size_t)row * 64 + k4 * 4);
        *(float4*)(&xs[r][k4 * 4]) = v;
    }
    for (int id = t; id < 64 * 40; id += 256) ws[id / 40][id % 40] = W2[id];
    __syncthreads();

    const int cc = c < 40 ? c : 0;
    float acc[8];
#pragma unroll
    for (int i = 0; i < 8; ++i) acc[i] = 0.f;
#pragma unroll
    for (int k = 0; k < 64; ++k) {
        float w = ws[k][cc];
#pragma unroll
        for (int r8 = 0; r8 < 8; ++r8)
            acc[r8] += xs[wv * 8 + r8][k] * w;
    }

    float a_s = as2[cc], a_d = ad2[cc];
#pragma unroll
    for (int r8 = 0; r8 < 8; ++r8) {
        int row = row0 + wv * 8 + r8;
        if (row < N && c < 40) h2b[(size_t)row * 40 + c] = __float2bfloat16(acc[r8]);
        float vs = (c < 40) ? acc[r8] * a_s : 0.f;
        float vd = (c < 40) ? acc[r8] * a_d : 0.f;
#pragma unroll
        for (int off = 1; off < 64; off <<= 1) {
            vs += __shfl_xor(vs, off);
            vd += __shfl_xor(vd, off);
        }
        if (c == 0 && row < N) { al2s[row] = vs; al2d[row] = vd; }
    }
}

// ---------------- agg2: per-dst-node softmax + aggregate + bias + log-softmax ----------------
__global__ __launch_bounds__(256) void agg2_kernel(
    const int* __restrict__ rowptr, const int* __restrict__ srcs,
    const __hip_bfloat16* __restrict__ h2b,
    const float* __restrict__ s2, const float* __restrict__ d2,
    const float* __restrict__ b2, float* __restrict__ out, int N)
{
    int lane = threadIdx.x & 63, wv = threadIdx.x >> 6;
    int n = blockIdx.x * 4 + wv;
    if (n >= N) return;
    bool act = lane < 40;
    float dn = d2[n];
    float p = __expf(leaky(s2[n] + dn));
    float den = p;
    float acc = act ? p * __bfloat162float(h2b[(size_t)n * 40 + lane]) : 0.f;
    int beg = rowptr[n], end = rowptr[n + 1];
    for (int i = beg; i < end; ++i) {
        int s = srcs[i];
        float pe = __expf(leaky(s2[s] + dn));
        den += pe;
        if (act) acc += pe * __bfloat162float(h2b[(size_t)s * 40 + lane]);
    }
    float v = act ? acc / den + b2[lane] : -INFINITY;
    float m = v;
#pragma unroll
    for (int off = 1; off < 64; off <<= 1) m = fmaxf(m, __shfl_xor(m, off));
    float e = act ? __expf(v - m) : 0.f;
    float sum = e;
#pragma unroll
    for (int off = 1; off < 64; off <<= 1) sum += __shfl_xor(sum, off);
    if (act) out[(size_t)n * 40 + lane] = v - m - logf(sum);
}

extern "C" void kernel_launch(void* const* d_in, const int* in_sizes, int n_in,
                              void* d_out, int out_size, void* d_ws, size_t ws_size,
                              hipStream_t stream)
{
    const float*    x    = (const float*)d_in[0];
    const unsigned* eraw = (const unsigned*)d_in[1];
    const float*    W1   = (const float*)d_in[2];
    const float*    as1  = (const float*)d_in[3];
    const float*    ad1  = (const float*)d_in[4];
    const float*    b1   = (const float*)d_in[5];
    const float*    W2   = (const float*)d_in[6];
    const float*    as2  = (const float*)d_in[7];
    const float*    ad2  = (const float*)d_in[8];
    const float*    b2   = (const float*)d_in[9];
    float* out = (float*)d_out;

    const int N = in_sizes[0] / 256;
    const int E = in_sizes[1] / 2;
    const int NB = (N + CHUNK - 1) / CHUNK;

    char* ws = (char*)d_ws;
    size_t off = 0;
    auto alloc = [&](size_t bytes) {
        size_t o = off;
        off = (off + bytes + 255) & ~(size_t)255;
        return o;
    };
    int*   edges   = (int*)  (ws + alloc((size_t)2 * E * 4));
    int*   ssorted = (int*)  (ws + alloc((size_t)E * 4));
    int*   rowptr  = (int*)  (ws + alloc((size_t)(N + 1) * 4));
    int*   deg     = (int*)  (ws + alloc((size_t)N * 4));
    int*   cur     = (int*)  (ws + alloc((size_t)N * 4));
    int*   csum    = (int*)  (ws + alloc((size_t)NB * 4));
    int*   coff    = (int*)  (ws + alloc((size_t)NB * 4));
    int*   flag    = (int*)  (ws + alloc(256));
    __hip_bfloat16* h1b = (__hip_bfloat16*)(ws + alloc((size_t)N * 64 * 2));
    __hip_bfloat16* h2b = (__hip_bfloat16*)(ws + alloc((size_t)N * 40 * 2));
    float* als1 = (float*)(ws + alloc((size_t)N * 8 * 4));
    float* ald1 = (float*)(ws + alloc((size_t)N * 8 * 4));
    float* x2   = (float*)(ws + alloc((size_t)N * 64 * 4));
    float* al2s = (float*)(ws + alloc((size_t)N * 4));
    float* al2d = (float*)(ws + alloc((size_t)N * 4));

    dim3 B(256);
    detect_kernel<<<1, B, 0, stream>>>(eraw, flag);
    convert_kernel<<<dim3((2 * E + 255) / 256), B, 0, stream>>>(eraw, edges, flag, 2 * E);

    // CSR build (dst-sorted)
    zero2_kernel<<<dim3((N + 255) / 256), B, 0, stream>>>(deg, cur, N);
    hist_kernel<<<dim3((E + 255) / 256), B, 0, stream>>>(edges, deg, E);
    chunksum_kernel<<<dim3(NB), B, 0, stream>>>(deg, csum, N);
    chunkscan_kernel<<<1, dim3(64), 0, stream>>>(csum, coff, rowptr + N, NB, E);
    writeptr_kernel<<<dim3(NB), B, 0, stream>>>(deg, coff, rowptr, N);
    scatter_kernel<<<dim3((E + 255) / 256), B, 0, stream>>>(edges, rowptr, cur, ssorted, E);

    // layer 1
    gemm1_kernel<<<dim3((N + 31) / 32), B, 0, stream>>>(x, W1, as1, ad1, h1b, als1, ald1, N);
    agg1_kernel<<<dim3((N + 3) / 4), B, 0, stream>>>(rowptr, ssorted, h1b, als1, ald1, b1, x2, N);

    // layer 2
    gemm2_kernel<<<dim3((N + 31) / 32), B, 0, stream>>>(x2, W2, as2, ad2, h2b, al2s, al2d, N);
    agg2_kernel<<<dim3((N + 3) / 4), B, 0, stream>>>(rowptr, ssorted, h2b, al2s, al2d, b2, out, N);
}

// Round 3
// 649.498 us; speedup vs baseline: 1.7035x; 1.2310x over previous
//
#include <hip/hip_runtime.h>
#include <hip/hip_bf16.h>
#include <math.h>

#define NEG_SLOPE 0.2f
#define CHUNK 1024

__device__ __forceinline__ float leaky(float v) { return v >= 0.f ? v : NEG_SLOPE * v; }

// ---------------- edge dtype detect + convert ----------------
__global__ void detect_kernel(const unsigned* __restrict__ w, int* __restrict__ flag)
{
    __shared__ int anynz;
    if (threadIdx.x == 0) anynz = 0;
    __syncthreads();
    bool nz = false;
#pragma unroll
    for (int j = 0; j < 8; ++j) {
        int idx = 2 * (threadIdx.x + 256 * j) + 1;
        nz |= (w[idx] != 0u);
    }
    if (nz) anynz = 1;
    __syncthreads();
    if (threadIdx.x == 0) *flag = anynz ? 0 : 1;     // 1 => int64 layout
}

__global__ void convert_kernel(const unsigned* __restrict__ w, int* __restrict__ out,
                               const int* __restrict__ flag, int n)
{
    int id = blockIdx.x * 256 + threadIdx.x;
    if (id >= n) return;
    int f = *flag;
    out[id] = (int)(f ? w[2 * id] : w[id]);
}

// ---------------- CSR build (dst-sorted) ----------------
__global__ void zero2_kernel(int* __restrict__ deg, int* __restrict__ cur, int N)
{
    int id = blockIdx.x * 256 + threadIdx.x;
    if (id < N) { deg[id] = 0; cur[id] = 0; }
}

__global__ void hist_kernel(const int* __restrict__ eg, int* __restrict__ deg, int E)
{
    int e = blockIdx.x * 256 + threadIdx.x;
    if (e < E) atomicAdd(&deg[eg[E + e]], 1);
}

__global__ void chunksum_kernel(const int* __restrict__ deg, int* __restrict__ csum, int N)
{
    int b = blockIdx.x, t = threadIdx.x;
    int base = b * CHUNK + t * 4;
    int s = 0;
#pragma unroll
    for (int j = 0; j < 4; ++j) { int i = base + j; if (i < N) s += deg[i]; }
#pragma unroll
    for (int off = 1; off < 64; off <<= 1) s += __shfl_xor(s, off);
    __shared__ int wt[4];
    if ((t & 63) == 0) wt[t >> 6] = s;
    __syncthreads();
    if (t == 0) csum[b] = wt[0] + wt[1] + wt[2] + wt[3];
}

// single wave; NB <= 128
__global__ void chunkscan_kernel(const int* __restrict__ csum, int* __restrict__ coff,
                                 int* __restrict__ rowptrN, int NB, int E)
{
    int lane = threadIdx.x;
    int v0 = (lane < NB) ? csum[lane] : 0;
    int v1 = (lane + 64 < NB) ? csum[lane + 64] : 0;
    int s0 = v0;
#pragma unroll
    for (int off = 1; off < 64; off <<= 1) { int u = __shfl_up(s0, off); if (lane >= off) s0 += u; }
    int tot0 = __shfl(s0, 63);
    if (lane < NB) coff[lane] = s0 - v0;
    int s1 = v1;
#pragma unroll
    for (int off = 1; off < 64; off <<= 1) { int u = __shfl_up(s1, off); if (lane >= off) s1 += u; }
    if (lane + 64 < NB) coff[lane + 64] = tot0 + s1 - v1;
    if (lane == 0) *rowptrN = E;
}

__global__ void writeptr_kernel(const int* __restrict__ deg, const int* __restrict__ coff,
                                int* __restrict__ rowptr, int N)
{
    int b = blockIdx.x, t = threadIdx.x;
    int base = b * CHUNK + t * 4;
    int d[4]; int s = 0;
#pragma unroll
    for (int j = 0; j < 4; ++j) { int i = base + j; d[j] = (i < N) ? deg[i] : 0; s += d[j]; }
    int lane = t & 63, wv = t >> 6;
    int incl = s;
#pragma unroll
    for (int off = 1; off < 64; off <<= 1) { int u = __shfl_up(incl, off); if (lane >= off) incl += u; }
    __shared__ int wt[4];
    if (lane == 63) wt[wv] = incl;
    __syncthreads();
    int wbase = 0;
    for (int w = 0; w < wv; ++w) wbase += wt[w];
    int run = wbase + incl - s + coff[b];
#pragma unroll
    for (int j = 0; j < 4; ++j) { int i = base + j; if (i < N) rowptr[i] = run; run += d[j]; }
}

__global__ void scatter_kernel(const int* __restrict__ eg, const int* __restrict__ rowptr,
                               int* __restrict__ cur, int* __restrict__ ssorted, int E)
{
    int e = blockIdx.x * 256 + threadIdx.x;
    if (e >= E) return;
    int dst = eg[E + e];
    int k = atomicAdd(&cur[dst], 1);
    ssorted[rowptr[dst] + k] = eg[e];
}

// ---------------- GEMM1: h1 = x @ W1 (bf16 out), fused attention logits ----------------
__global__ __launch_bounds__(256) void gemm1_kernel(
    const float* __restrict__ x, const float* __restrict__ W,
    const float* __restrict__ as1, const float* __restrict__ ad1,
    __hip_bfloat16* __restrict__ h1b, float* __restrict__ als, float* __restrict__ ald, int N)
{
    __shared__ float xs[32][64];
    __shared__ float ws[64][68];
    const int t = threadIdx.x;
    const int c = t & 63;
    const int wv = t >> 6;
    const int row0 = blockIdx.x * 32;

    float acc[8];
#pragma unroll
    for (int i = 0; i < 8; ++i) acc[i] = 0.f;

    for (int kc = 0; kc < 4; ++kc) {
#pragma unroll
        for (int j = 0; j < 2; ++j) {
            int id = t + 256 * j;
            int r = id >> 4, k4 = id & 15;
            int row = row0 + r;
            float4 v = make_float4(0.f, 0.f, 0.f, 0.f);
            if (row < N) v = *(const float4*)(x + (size_t)row * 256 + kc * 64 + k4 * 4);
            *(float4*)(&xs[r][k4 * 4]) = v;
        }
#pragma unroll
        for (int j = 0; j < 4; ++j) {
            int id = t + 256 * j;
            int k = id >> 4, c4 = id & 15;
            float4 v = *(const float4*)(W + (size_t)(kc * 64 + k) * 64 + c4 * 4);
            *(float4*)(&ws[k][c4 * 4]) = v;
        }
        __syncthreads();
#pragma unroll
        for (int k = 0; k < 64; ++k) {
            float w = ws[k][c];
#pragma unroll
            for (int r8 = 0; r8 < 8; ++r8)
                acc[r8] += xs[wv * 8 + r8][k] * w;
        }
        __syncthreads();
    }

    float a_s = as1[c], a_d = ad1[c];
#pragma unroll
    for (int r8 = 0; r8 < 8; ++r8) {
        int row = row0 + wv * 8 + r8;
        if (row < N) h1b[(size_t)row * 64 + c] = __float2bfloat16(acc[r8]);
        float vs = acc[r8] * a_s, vd = acc[r8] * a_d;
#pragma unroll
        for (int off = 1; off < 8; off <<= 1) {
            vs += __shfl_xor(vs, off);
            vd += __shfl_xor(vd, off);
        }
        if ((c & 7) == 0 && row < N) {
            als[row * 8 + (c >> 3)] = vs;
            ald[row * 8 + (c >> 3)] = vd;
        }
    }
}

// ---------------- agg1: per-dst-node softmax + aggregate + bias + ELU ----------------
// 8-wide ILP: 8 edge indices loaded, then 16 independent gathers in flight.
__global__ __launch_bounds__(256) void agg1_kernel(
    const int* __restrict__ rowptr, const int* __restrict__ srcs,
    const __hip_bfloat16* __restrict__ h1b,
    const float* __restrict__ als, const float* __restrict__ ald,
    const float* __restrict__ b1, float* __restrict__ x2, int N)
{
    int lane = threadIdx.x & 63, wv = threadIdx.x >> 6;
    int n = blockIdx.x * 4 + wv;
    if (n >= N) return;
    int hb = lane >> 3;                    // head for this channel
    float aldn = ald[n * 8 + hb];
    float alsn = als[n * 8 + hb];
    // self-loop
    float p = __expf(leaky(alsn + aldn));
    float den = p;
    float acc = p * __bfloat162float(h1b[(size_t)n * 64 + lane]);
    int beg = rowptr[n], end = rowptr[n + 1];
    for (int i = beg; i < end; i += 8) {
        int idx[8];
#pragma unroll
        for (int j = 0; j < 8; ++j) {
            int ii = i + j;
            idx[j] = srcs[ii < end ? ii : end - 1];
        }
        float hv[8], av[8];
#pragma unroll
        for (int j = 0; j < 8; ++j)
            hv[j] = __bfloat162float(h1b[(size_t)idx[j] * 64 + lane]);
#pragma unroll
        for (int j = 0; j < 8; ++j)
            av[j] = als[idx[j] * 8 + hb];
#pragma unroll
        for (int j = 0; j < 8; ++j) {
            float pe = (i + j < end) ? __expf(leaky(av[j] + aldn)) : 0.f;
            den += pe;
            acc += pe * hv[j];
        }
    }
    float v = acc / den + b1[lane];
    x2[(size_t)n * 64 + lane] = v > 0.f ? v : expm1f(v);
}

// ---------------- GEMM2: h2 = x2 @ W2 (bf16 out), fused single-head logits ----------------
__global__ __launch_bounds__(256) void gemm2_kernel(
    const float* __restrict__ x2, const float* __restrict__ W2,
    const float* __restrict__ as2, const float* __restrict__ ad2,
    __hip_bfloat16* __restrict__ h2b, float* __restrict__ al2s, float* __restrict__ al2d, int N)
{
    __shared__ float xs[32][64];
    __shared__ float ws[64][40];
    const int t = threadIdx.x;
    const int c = t & 63;
    const int wv = t >> 6;
    const int row0 = blockIdx.x * 32;

#pragma unroll
    for (int j = 0; j < 2; ++j) {
        int id = t + 256 * j;
        int r = id >> 4, k4 = id & 15;
        int row = row0 + r;
        float4 v = make_float4(0.f, 0.f, 0.f, 0.f);
        if (row < N) v = *(const float4*)(x2 + (size_t)row * 64 + k4 * 4);
        *(float4*)(&xs[r][k4 * 4]) = v;
    }
    for (int id = t; id < 64 * 40; id += 256) ws[id / 40][id % 40] = W2[id];
    __syncthreads();

    const int cc = c < 40 ? c : 0;
    float acc[8];
#pragma unroll
    for (int i = 0; i < 8; ++i) acc[i] = 0.f;
#pragma unroll
    for (int k = 0; k < 64; ++k) {
        float w = ws[k][cc];
#pragma unroll
        for (int r8 = 0; r8 < 8; ++r8)
            acc[r8] += xs[wv * 8 + r8][k] * w;
    }

    float a_s = as2[cc], a_d = ad2[cc];
#pragma unroll
    for (int r8 = 0; r8 < 8; ++r8) {
        int row = row0 + wv * 8 + r8;
        if (row < N && c < 40) h2b[(size_t)row * 40 + c] = __float2bfloat16(acc[r8]);
        float vs = (c < 40) ? acc[r8] * a_s : 0.f;
        float vd = (c < 40) ? acc[r8] * a_d : 0.f;
#pragma unroll
        for (int off = 1; off < 64; off <<= 1) {
            vs += __shfl_xor(vs, off);
            vd += __shfl_xor(vd, off);
        }
        if (c == 0 && row < N) { al2s[row] = vs; al2d[row] = vd; }
    }
}

// ---------------- agg2: per-dst-node softmax + aggregate + bias + log-softmax ----------------
__global__ __launch_bounds__(256) void agg2_kernel(
    const int* __restrict__ rowptr, const int* __restrict__ srcs,
    const __hip_bfloat16* __restrict__ h2b,
    const float* __restrict__ s2, const float* __restrict__ d2,
    const float* __restrict__ b2, float* __restrict__ out, int N)
{
    int lane = threadIdx.x & 63, wv = threadIdx.x >> 6;
    int n = blockIdx.x * 4 + wv;
    if (n >= N) return;
    bool act = lane < 40;
    float dn = d2[n];
    float p = __expf(leaky(s2[n] + dn));
    float den = p;
    float acc = act ? p * __bfloat162float(h2b[(size_t)n * 40 + lane]) : 0.f;
    int beg = rowptr[n], end = rowptr[n + 1];
    for (int i = beg; i < end; i += 8) {
        int idx[8];
#pragma unroll
        for (int j = 0; j < 8; ++j) {
            int ii = i + j;
            idx[j] = srcs[ii < end ? ii : end - 1];
        }
        float hv[8], av[8];
#pragma unroll
        for (int j = 0; j < 8; ++j)
            hv[j] = act ? __bfloat162float(h2b[(size_t)idx[j] * 40 + lane]) : 0.f;
#pragma unroll
        for (int j = 0; j < 8; ++j)
            av[j] = s2[idx[j]];
#pragma unroll
        for (int j = 0; j < 8; ++j) {
            float pe = (i + j < end) ? __expf(leaky(av[j] + dn)) : 0.f;
            den += pe;
            acc += pe * hv[j];
        }
    }
    float v = act ? acc / den + b2[lane] : -INFINITY;
    float m = v;
#pragma unroll
    for (int off = 1; off < 64; off <<= 1) m = fmaxf(m, __shfl_xor(m, off));
    float e = act ? __expf(v - m) : 0.f;
    float sum = e;
#pragma unroll
    for (int off = 1; off < 64; off <<= 1) sum += __shfl_xor(sum, off);
    if (act) out[(size_t)n * 40 + lane] = v - m - logf(sum);
}

extern "C" void kernel_launch(void* const* d_in, const int* in_sizes, int n_in,
                              void* d_out, int out_size, void* d_ws, size_t ws_size,
                              hipStream_t stream)
{
    const float*    x    = (const float*)d_in[0];
    const unsigned* eraw = (const unsigned*)d_in[1];
    const float*    W1   = (const float*)d_in[2];
    const float*    as1  = (const float*)d_in[3];
    const float*    ad1  = (const float*)d_in[4];
    const float*    b1   = (const float*)d_in[5];
    const float*    W2   = (const float*)d_in[6];
    const float*    as2  = (const float*)d_in[7];
    const float*    ad2  = (const float*)d_in[8];
    const float*    b2   = (const float*)d_in[9];
    float* out = (float*)d_out;

    const int N = in_sizes[0] / 256;
    const int E = in_sizes[1] / 2;
    const int NB = (N + CHUNK - 1) / CHUNK;

    char* ws = (char*)d_ws;
    size_t off = 0;
    auto alloc = [&](size_t bytes) {
        size_t o = off;
        off = (off + bytes + 255) & ~(size_t)255;
        return o;
    };
    int*   edges   = (int*)  (ws + alloc((size_t)2 * E * 4));
    int*   ssorted = (int*)  (ws + alloc((size_t)E * 4));
    int*   rowptr  = (int*)  (ws + alloc((size_t)(N + 1) * 4));
    int*   deg     = (int*)  (ws + alloc((size_t)N * 4));
    int*   cur     = (int*)  (ws + alloc((size_t)N * 4));
    int*   csum    = (int*)  (ws + alloc((size_t)NB * 4));
    int*   coff    = (int*)  (ws + alloc((size_t)NB * 4));
    int*   flag    = (int*)  (ws + alloc(256));
    __hip_bfloat16* h1b = (__hip_bfloat16*)(ws + alloc((size_t)N * 64 * 2));
    __hip_bfloat16* h2b = (__hip_bfloat16*)(ws + alloc((size_t)N * 40 * 2));
    float* als1 = (float*)(ws + alloc((size_t)N * 8 * 4));
    float* ald1 = (float*)(ws + alloc((size_t)N * 8 * 4));
    float* x2   = (float*)(ws + alloc((size_t)N * 64 * 4));
    float* al2s = (float*)(ws + alloc((size_t)N * 4));
    float* al2d = (float*)(ws + alloc((size_t)N * 4));

    dim3 B(256);
    detect_kernel<<<1, B, 0, stream>>>(eraw, flag);
    convert_kernel<<<dim3((2 * E + 255) / 256), B, 0, stream>>>(eraw, edges, flag, 2 * E);

    // CSR build (dst-sorted)
    zero2_kernel<<<dim3((N + 255) / 256), B, 0, stream>>>(deg, cur, N);
    hist_kernel<<<dim3((E + 255) / 256), B, 0, stream>>>(edges, deg, E);
    chunksum_kernel<<<dim3(NB), B, 0, stream>>>(deg, csum, N);
    chunkscan_kernel<<<1, dim3(64), 0, stream>>>(csum, coff, rowptr + N, NB, E);
    writeptr_kernel<<<dim3(NB), B, 0, stream>>>(deg, coff, rowptr, N);
    scatter_kernel<<<dim3((E + 255) / 256), B, 0, stream>>>(edges, rowptr, cur, ssorted, E);

    // layer 1
    gemm1_kernel<<<dim3((N + 31) / 32), B, 0, stream>>>(x, W1, as1, ad1, h1b, als1, ald1, N);
    agg1_kernel<<<dim3((N + 3) / 4), B, 0, stream>>>(rowptr, ssorted, h1b, als1, ald1, b1, x2, N);

    // layer 2
    gemm2_kernel<<<dim3((N + 31) / 32), B, 0, stream>>>(x2, W2, as2, ad2, h2b, al2s, al2d, N);
    agg2_kernel<<<dim3((N + 3) / 4), B, 0, stream>>>(rowptr, ssorted, h2b, al2s, al2d, b2, out, N);
}

// Round 4
// 470.327 us; speedup vs baseline: 2.3524x; 1.3810x over previous
//
#include <hip/hip_runtime.h>
#include <hip/hip_bf16.h>
#include <math.h>

#define NEG_SLOPE 0.2f
#define CHUNK 1024

typedef __attribute__((ext_vector_type(8))) short short8;
typedef __attribute__((ext_vector_type(4))) float f32x4;

__device__ __forceinline__ float leaky(float v) { return v >= 0.f ? v : NEG_SLOPE * v; }

// fp32 -> bf16 RNE (bit trick, finite inputs)
__device__ __forceinline__ short bfr(float f)
{
    union { float f; unsigned u; } v; v.f = f;
    unsigned r = (v.u + 0x7FFFu + ((v.u >> 16) & 1u)) >> 16;
    return (short)r;
}

// ---------------- edge dtype detect + convert ----------------
__global__ void detect_kernel(const unsigned* __restrict__ w, int* __restrict__ flag)
{
    __shared__ int anynz;
    if (threadIdx.x == 0) anynz = 0;
    __syncthreads();
    bool nz = false;
#pragma unroll
    for (int j = 0; j < 8; ++j) {
        int idx = 2 * (threadIdx.x + 256 * j) + 1;
        nz |= (w[idx] != 0u);
    }
    if (nz) anynz = 1;
    __syncthreads();
    if (threadIdx.x == 0) *flag = anynz ? 0 : 1;     // 1 => int64 layout
}

__global__ void convert_kernel(const unsigned* __restrict__ w, int* __restrict__ out,
                               const int* __restrict__ flag, int n)
{
    int id = blockIdx.x * 256 + threadIdx.x;
    if (id >= n) return;
    int f = *flag;
    out[id] = (int)(f ? w[2 * id] : w[id]);
}

// ---------------- weight transposes (bf16) ----------------
__global__ void w1t_kernel(const float* __restrict__ W1, short* __restrict__ W1Tb)
{
    int id = blockIdx.x * 256 + threadIdx.x;      // 256*64
    if (id >= 256 * 64) return;
    int k = id >> 6, c = id & 63;
    W1Tb[c * 256 + k] = bfr(W1[id]);
}

__global__ void w2t_kernel(const float* __restrict__ W2, short* __restrict__ W2Tb)
{
    int id = blockIdx.x * 256 + threadIdx.x;      // 48*64
    if (id >= 48 * 64) return;
    int n = id >> 6, k = id & 63;
    W2Tb[id] = (n < 40) ? bfr(W2[k * 40 + n]) : (short)0;
}

// ---------------- CSR build (dst-sorted) ----------------
__global__ void zero2_kernel(int* __restrict__ deg, int* __restrict__ cur, int N)
{
    int id = blockIdx.x * 256 + threadIdx.x;
    if (id < N) { deg[id] = 0; cur[id] = 0; }
}

__global__ void hist_kernel(const int* __restrict__ eg, int* __restrict__ deg, int E)
{
    int e = blockIdx.x * 256 + threadIdx.x;
    if (e < E) atomicAdd(&deg[eg[E + e]], 1);
}

__global__ void chunksum_kernel(const int* __restrict__ deg, int* __restrict__ csum, int N)
{
    int b = blockIdx.x, t = threadIdx.x;
    int base = b * CHUNK + t * 4;
    int s = 0;
#pragma unroll
    for (int j = 0; j < 4; ++j) { int i = base + j; if (i < N) s += deg[i]; }
#pragma unroll
    for (int off = 1; off < 64; off <<= 1) s += __shfl_xor(s, off);
    __shared__ int wt[4];
    if ((t & 63) == 0) wt[t >> 6] = s;
    __syncthreads();
    if (t == 0) csum[b] = wt[0] + wt[1] + wt[2] + wt[3];
}

// single wave; NB <= 128
__global__ void chunkscan_kernel(const int* __restrict__ csum, int* __restrict__ coff,
                                 int* __restrict__ rowptrN, int NB, int E)
{
    int lane = threadIdx.x;
    int v0 = (lane < NB) ? csum[lane] : 0;
    int v1 = (lane + 64 < NB) ? csum[lane + 64] : 0;
    int s0 = v0;
#pragma unroll
    for (int off = 1; off < 64; off <<= 1) { int u = __shfl_up(s0, off); if (lane >= off) s0 += u; }
    int tot0 = __shfl(s0, 63);
    if (lane < NB) coff[lane] = s0 - v0;
    int s1 = v1;
#pragma unroll
    for (int off = 1; off < 64; off <<= 1) { int u = __shfl_up(s1, off); if (lane >= off) s1 += u; }
    if (lane + 64 < NB) coff[lane + 64] = tot0 + s1 - v1;
    if (lane == 0) *rowptrN = E;
}

__global__ void writeptr_kernel(const int* __restrict__ deg, const int* __restrict__ coff,
                                int* __restrict__ rowptr, int N)
{
    int b = blockIdx.x, t = threadIdx.x;
    int base = b * CHUNK + t * 4;
    int d[4]; int s = 0;
#pragma unroll
    for (int j = 0; j < 4; ++j) { int i = base + j; d[j] = (i < N) ? deg[i] : 0; s += d[j]; }
    int lane = t & 63, wv = t >> 6;
    int incl = s;
#pragma unroll
    for (int off = 1; off < 64; off <<= 1) { int u = __shfl_up(incl, off); if (lane >= off) incl += u; }
    __shared__ int wt[4];
    if (lane == 63) wt[wv] = incl;
    __syncthreads();
    int wbase = 0;
    for (int w = 0; w < wv; ++w) wbase += wt[w];
    int run = wbase + incl - s + coff[b];
#pragma unroll
    for (int j = 0; j < 4; ++j) { int i = base + j; if (i < N) rowptr[i] = run; run += d[j]; }
}

__global__ void scatter_kernel(const int* __restrict__ eg, const int* __restrict__ rowptr,
                               int* __restrict__ cur, int* __restrict__ ssorted, int E)
{
    int e = blockIdx.x * 256 + threadIdx.x;
    if (e >= E) return;
    int dst = eg[E + e];
    int k = atomicAdd(&cur[dst], 1);
    ssorted[rowptr[dst] + k] = eg[e];
}

// ---------------- GEMM1 (MFMA): h1 = x @ W1, fused per-head logits ----------------
// Block: 64 rows; wave: 16 rows x 64 cols (4 n-tiles of 16x16, K=256 in 8 steps).
// No LDS: A frags converted fp32->bf16 in-register; B frags are L1-hot global loads.
__global__ __launch_bounds__(256) void gemm1_kernel(
    const float* __restrict__ x, const short* __restrict__ W1Tb,
    const float* __restrict__ as1, const float* __restrict__ ad1,
    __hip_bfloat16* __restrict__ h1b, float* __restrict__ als, float* __restrict__ ald, int N)
{
    const int l = threadIdx.x & 63, wv = threadIdx.x >> 6;
    const int m = l & 15, g = l >> 4;
    const int arow = blockIdx.x * 64 + wv * 16 + m;    // A-frag row
    const bool rv = arow < N;
    const float* xrow = x + (size_t)arow * 256;

    f32x4 acc[4] = {f32x4{0,0,0,0}, f32x4{0,0,0,0}, f32x4{0,0,0,0}, f32x4{0,0,0,0}};

#pragma unroll
    for (int ks = 0; ks < 8; ++ks) {
        const int k0 = ks * 32 + g * 8;
        float xa[8];
        if (rv) {
            float4 v0 = *(const float4*)(xrow + k0);
            float4 v1 = *(const float4*)(xrow + k0 + 4);
            xa[0] = v0.x; xa[1] = v0.y; xa[2] = v0.z; xa[3] = v0.w;
            xa[4] = v1.x; xa[5] = v1.y; xa[6] = v1.z; xa[7] = v1.w;
        } else {
#pragma unroll
            for (int j = 0; j < 8; ++j) xa[j] = 0.f;
        }
        short8 af;
#pragma unroll
        for (int j = 0; j < 8; ++j) af[j] = bfr(xa[j]);
#pragma unroll
        for (int nt = 0; nt < 4; ++nt) {
            short8 bf_ = *(const short8*)(W1Tb + (size_t)(nt * 16 + m) * 256 + k0);
            acc[nt] = __builtin_amdgcn_mfma_f32_16x16x32_bf16(af, bf_, acc[nt], 0, 0, 0);
        }
    }

    // epilogue: h1b store + per-head attention logits
    const int orow0 = blockIdx.x * 64 + wv * 16 + g * 4;
    float a_sv[4], a_dv[4];
#pragma unroll
    for (int nt = 0; nt < 4; ++nt) { a_sv[nt] = as1[nt * 16 + m]; a_dv[nt] = ad1[nt * 16 + m]; }

    float vs[4][4], vd[4][4];
#pragma unroll
    for (int nt = 0; nt < 4; ++nt)
#pragma unroll
        for (int r = 0; r < 4; ++r) {
            vs[nt][r] = acc[nt][r] * a_sv[nt];
            vd[nt][r] = acc[nt][r] * a_dv[nt];
        }
#pragma unroll
    for (int off = 1; off < 8; off <<= 1)
#pragma unroll
        for (int nt = 0; nt < 4; ++nt)
#pragma unroll
            for (int r = 0; r < 4; ++r) {
                vs[nt][r] += __shfl_xor(vs[nt][r], off);
                vd[nt][r] += __shfl_xor(vd[nt][r], off);
            }

#pragma unroll
    for (int nt = 0; nt < 4; ++nt)
#pragma unroll
        for (int r = 0; r < 4; ++r) {
            int row = orow0 + r;
            if (row < N) h1b[(size_t)row * 64 + nt * 16 + m] = __float2bfloat16(acc[nt][r]);
        }
    if ((l & 7) == 0) {
        int par = m >> 3;
#pragma unroll
        for (int nt = 0; nt < 4; ++nt)
#pragma unroll
            for (int r = 0; r < 4; ++r) {
                int row = orow0 + r;
                if (row < N) {
                    als[row * 8 + 2 * nt + par] = vs[nt][r];
                    ald[row * 8 + 2 * nt + par] = vd[nt][r];
                }
            }
    }
}

// ---------------- agg1: per-dst-node softmax + aggregate + bias + ELU ----------------
__global__ __launch_bounds__(256) void agg1_kernel(
    const int* __restrict__ rowptr, const int* __restrict__ srcs,
    const __hip_bfloat16* __restrict__ h1b,
    const float* __restrict__ als, const float* __restrict__ ald,
    const float* __restrict__ b1, float* __restrict__ x2, int N)
{
    int lane = threadIdx.x & 63, wv = threadIdx.x >> 6;
    int n = blockIdx.x * 4 + wv;
    if (n >= N) return;
    int hb = lane >> 3;
    float aldn = ald[n * 8 + hb];
    float alsn = als[n * 8 + hb];
    float p = __expf(leaky(alsn + aldn));
    float den = p;
    float acc = p * __bfloat162float(h1b[(size_t)n * 64 + lane]);
    int beg = rowptr[n], end = rowptr[n + 1];
    for (int i = beg; i < end; i += 8) {
        int idx[8];
#pragma unroll
        for (int j = 0; j < 8; ++j) {
            int ii = i + j;
            idx[j] = srcs[ii < end ? ii : end - 1];
        }
        float hv[8], av[8];
#pragma unroll
        for (int j = 0; j < 8; ++j)
            hv[j] = __bfloat162float(h1b[(size_t)idx[j] * 64 + lane]);
#pragma unroll
        for (int j = 0; j < 8; ++j)
            av[j] = als[idx[j] * 8 + hb];
#pragma unroll
        for (int j = 0; j < 8; ++j) {
            float pe = (i + j < end) ? __expf(leaky(av[j] + aldn)) : 0.f;
            den += pe;
            acc += pe * hv[j];
        }
    }
    float v = acc / den + b1[lane];
    x2[(size_t)n * 64 + lane] = v > 0.f ? v : expm1f(v);
}

// ---------------- GEMM2 (MFMA): h2 = x2 @ W2, fused single-head logits ----------------
__global__ __launch_bounds__(256) void gemm2_kernel(
    const float* __restrict__ x2, const short* __restrict__ W2Tb,
    const float* __restrict__ as2, const float* __restrict__ ad2,
    __hip_bfloat16* __restrict__ h2b, float* __restrict__ al2s, float* __restrict__ al2d, int N)
{
    const int l = threadIdx.x & 63, wv = threadIdx.x >> 6;
    const int m = l & 15, g = l >> 4;
    const int arow = blockIdx.x * 64 + wv * 16 + m;
    const bool rv = arow < N;
    const float* xrow = x2 + (size_t)arow * 64;

    f32x4 acc[3] = {f32x4{0,0,0,0}, f32x4{0,0,0,0}, f32x4{0,0,0,0}};

#pragma unroll
    for (int ks = 0; ks < 2; ++ks) {
        const int k0 = ks * 32 + g * 8;
        float xa[8];
        if (rv) {
            float4 v0 = *(const float4*)(xrow + k0);
            float4 v1 = *(const float4*)(xrow + k0 + 4);
            xa[0] = v0.x; xa[1] = v0.y; xa[2] = v0.z; xa[3] = v0.w;
            xa[4] = v1.x; xa[5] = v1.y; xa[6] = v1.z; xa[7] = v1.w;
        } else {
#pragma unroll
            for (int j = 0; j < 8; ++j) xa[j] = 0.f;
        }
        short8 af;
#pragma unroll
        for (int j = 0; j < 8; ++j) af[j] = bfr(xa[j]);
#pragma unroll
        for (int nt = 0; nt < 3; ++nt) {
            short8 bf_ = *(const short8*)(W2Tb + (size_t)(nt * 16 + m) * 64 + k0);
            acc[nt] = __builtin_amdgcn_mfma_f32_16x16x32_bf16(af, bf_, acc[nt], 0, 0, 0);
        }
    }

    const int orow0 = blockIdx.x * 64 + wv * 16 + g * 4;
    float a_sv[3], a_dv[3];
#pragma unroll
    for (int nt = 0; nt < 3; ++nt) {
        int c = nt * 16 + m;
        a_sv[nt] = (c < 40) ? as2[c] : 0.f;
        a_dv[nt] = (c < 40) ? ad2[c] : 0.f;
    }
    float vs[4], vd[4];
#pragma unroll
    for (int r = 0; r < 4; ++r) {
        vs[r] = acc[0][r] * a_sv[0] + acc[1][r] * a_sv[1] + acc[2][r] * a_sv[2];
        vd[r] = acc[0][r] * a_dv[0] + acc[1][r] * a_dv[1] + acc[2][r] * a_dv[2];
    }
#pragma unroll
    for (int off = 1; off < 16; off <<= 1)
#pragma unroll
        for (int r = 0; r < 4; ++r) {
            vs[r] += __shfl_xor(vs[r], off);
            vd[r] += __shfl_xor(vd[r], off);
        }

#pragma unroll
    for (int nt = 0; nt < 3; ++nt) {
        int c = nt * 16 + m;
        if (c >= 40) continue;
#pragma unroll
        for (int r = 0; r < 4; ++r) {
            int row = orow0 + r;
            if (row < N) h2b[(size_t)row * 40 + c] = __float2bfloat16(acc[nt][r]);
        }
    }
    if (m == 0) {
#pragma unroll
        for (int r = 0; r < 4; ++r) {
            int row = orow0 + r;
            if (row < N) { al2s[row] = vs[r]; al2d[row] = vd[r]; }
        }
    }
}

// ---------------- agg2: per-dst-node softmax + aggregate + bias + log-softmax ----------------
__global__ __launch_bounds__(256) void agg2_kernel(
    const int* __restrict__ rowptr, const int* __restrict__ srcs,
    const __hip_bfloat16* __restrict__ h2b,
    const float* __restrict__ s2, const float* __restrict__ d2,
    const float* __restrict__ b2, float* __restrict__ out, int N)
{
    int lane = threadIdx.x & 63, wv = threadIdx.x >> 6;
    int n = blockIdx.x * 4 + wv;
    if (n >= N) return;
    bool act = lane < 40;
    float dn = d2[n];
    float p = __expf(leaky(s2[n] + dn));
    float den = p;
    float acc = act ? p * __bfloat162float(h2b[(size_t)n * 40 + lane]) : 0.f;
    int beg = rowptr[n], end = rowptr[n + 1];
    for (int i = beg; i < end; i += 8) {
        int idx[8];
#pragma unroll
        for (int j = 0; j < 8; ++j) {
            int ii = i + j;
            idx[j] = srcs[ii < end ? ii : end - 1];
        }
        float hv[8], av[8];
#pragma unroll
        for (int j = 0; j < 8; ++j)
            hv[j] = act ? __bfloat162float(h2b[(size_t)idx[j] * 40 + lane]) : 0.f;
#pragma unroll
        for (int j = 0; j < 8; ++j)
            av[j] = s2[idx[j]];
#pragma unroll
        for (int j = 0; j < 8; ++j) {
            float pe = (i + j < end) ? __expf(leaky(av[j] + dn)) : 0.f;
            den += pe;
            acc += pe * hv[j];
        }
    }
    float v = act ? acc / den + b2[lane] : -INFINITY;
    float m = v;
#pragma unroll
    for (int off = 1; off < 64; off <<= 1) m = fmaxf(m, __shfl_xor(m, off));
    float e = act ? __expf(v - m) : 0.f;
    float sum = e;
#pragma unroll
    for (int off = 1; off < 64; off <<= 1) sum += __shfl_xor(sum, off);
    if (act) out[(size_t)n * 40 + lane] = v - m - logf(sum);
}

extern "C" void kernel_launch(void* const* d_in, const int* in_sizes, int n_in,
                              void* d_out, int out_size, void* d_ws, size_t ws_size,
                              hipStream_t stream)
{
    const float*    x    = (const float*)d_in[0];
    const unsigned* eraw = (const unsigned*)d_in[1];
    const float*    W1   = (const float*)d_in[2];
    const float*    as1  = (const float*)d_in[3];
    const float*    ad1  = (const float*)d_in[4];
    const float*    b1   = (const float*)d_in[5];
    const float*    W2   = (const float*)d_in[6];
    const float*    as2  = (const float*)d_in[7];
    const float*    ad2  = (const float*)d_in[8];
    const float*    b2   = (const float*)d_in[9];
    float* out = (float*)d_out;

    const int N = in_sizes[0] / 256;
    const int E = in_sizes[1] / 2;
    const int NB = (N + CHUNK - 1) / CHUNK;

    char* ws = (char*)d_ws;
    size_t off = 0;
    auto alloc = [&](size_t bytes) {
        size_t o = off;
        off = (off + bytes + 255) & ~(size_t)255;
        return o;
    };
    int*   edges   = (int*)  (ws + alloc((size_t)2 * E * 4));
    int*   ssorted = (int*)  (ws + alloc((size_t)E * 4));
    int*   rowptr  = (int*)  (ws + alloc((size_t)(N + 1) * 4));
    int*   deg     = (int*)  (ws + alloc((size_t)N * 4));
    int*   cur     = (int*)  (ws + alloc((size_t)N * 4));
    int*   csum    = (int*)  (ws + alloc((size_t)NB * 4));
    int*   coff    = (int*)  (ws + alloc((size_t)NB * 4));
    int*   flag    = (int*)  (ws + alloc(256));
    short* W1Tb    = (short*)(ws + alloc((size_t)64 * 256 * 2));
    short* W2Tb    = (short*)(ws + alloc((size_t)48 * 64 * 2));
    __hip_bfloat16* h1b = (__hip_bfloat16*)(ws + alloc((size_t)N * 64 * 2));
    __hip_bfloat16* h2b = (__hip_bfloat16*)(ws + alloc((size_t)N * 40 * 2));
    float* als1 = (float*)(ws + alloc((size_t)N * 8 * 4));
    float* ald1 = (float*)(ws + alloc((size_t)N * 8 * 4));
    float* x2   = (float*)(ws + alloc((size_t)N * 64 * 4));
    float* al2s = (float*)(ws + alloc((size_t)N * 4));
    float* al2d = (float*)(ws + alloc((size_t)N * 4));

    dim3 B(256);
    detect_kernel<<<1, B, 0, stream>>>(eraw, flag);
    convert_kernel<<<dim3((2 * E + 255) / 256), B, 0, stream>>>(eraw, edges, flag, 2 * E);
    w1t_kernel<<<dim3(64), B, 0, stream>>>(W1, W1Tb);
    w2t_kernel<<<dim3(12), B, 0, stream>>>(W2, W2Tb);

    // CSR build (dst-sorted)
    zero2_kernel<<<dim3((N + 255) / 256), B, 0, stream>>>(deg, cur, N);
    hist_kernel<<<dim3((E + 255) / 256), B, 0, stream>>>(edges, deg, E);
    chunksum_kernel<<<dim3(NB), B, 0, stream>>>(deg, csum, N);
    chunkscan_kernel<<<1, dim3(64), 0, stream>>>(csum, coff, rowptr + N, NB, E);
    writeptr_kernel<<<dim3(NB), B, 0, stream>>>(deg, coff, rowptr, N);
    scatter_kernel<<<dim3((E + 255) / 256), B, 0, stream>>>(edges, rowptr, cur, ssorted, E);

    // layer 1
    gemm1_kernel<<<dim3((N + 63) / 64), B, 0, stream>>>(x, W1Tb, as1, ad1, h1b, als1, ald1, N);
    agg1_kernel<<<dim3((N + 3) / 4), B, 0, stream>>>(rowptr, ssorted, h1b, als1, ald1, b1, x2, N);

    // layer 2
    gemm2_kernel<<<dim3((N + 63) / 64), B, 0, stream>>>(x2, W2Tb, as2, ad2, h2b, al2s, al2d, N);
    agg2_kernel<<<dim3((N + 3) / 4), B, 0, stream>>>(rowptr, ssorted, h2b, al2s, al2d, b2, out, N);
}

// Round 5
// 468.866 us; speedup vs baseline: 2.3598x; 1.0031x over previous
//
#include <hip/hip_runtime.h>
#include <hip/hip_bf16.h>
#include <math.h>

#define NEG_SLOPE 0.2f
#define CHUNK 1024

typedef __attribute__((ext_vector_type(8))) short short8;
typedef __attribute__((ext_vector_type(4))) float f32x4;

__device__ __forceinline__ float leaky(float v) { return v >= 0.f ? v : NEG_SLOPE * v; }

// fp32 -> bf16 RNE (bit trick, finite inputs)
__device__ __forceinline__ short bfr(float f)
{
    union { float f; unsigned u; } v; v.f = f;
    unsigned r = (v.u + 0x7FFFu + ((v.u >> 16) & 1u)) >> 16;
    return (short)r;
}
// bf16 bits -> fp32
__device__ __forceinline__ float b2f(short s)
{
    union { unsigned u; float f; } v; v.u = ((unsigned)(unsigned short)s) << 16;
    return v.f;
}

// ---------------- edge dtype detect ----------------
__global__ void detect_kernel(const unsigned* __restrict__ w, int* __restrict__ flag)
{
    __shared__ int anynz;
    if (threadIdx.x == 0) anynz = 0;
    __syncthreads();
    bool nz = false;
#pragma unroll
    for (int j = 0; j < 8; ++j) {
        int idx = 2 * (threadIdx.x + 256 * j) + 1;
        nz |= (w[idx] != 0u);
    }
    if (nz) anynz = 1;
    __syncthreads();
    if (threadIdx.x == 0) *flag = anynz ? 0 : 1;     // 1 => int64 layout
}

// ---------------- weight transposes (bf16) ----------------
__global__ void w1t_kernel(const float* __restrict__ W1, short* __restrict__ W1Tb)
{
    int id = blockIdx.x * 256 + threadIdx.x;      // 256*64
    if (id >= 256 * 64) return;
    int k = id >> 6, c = id & 63;
    W1Tb[c * 256 + k] = bfr(W1[id]);
}

__global__ void w2t_kernel(const float* __restrict__ W2, short* __restrict__ W2Tb)
{
    int id = blockIdx.x * 256 + threadIdx.x;      // 48*64
    if (id >= 48 * 64) return;
    int n = id >> 6, k = id & 63;
    W2Tb[id] = (n < 40) ? bfr(W2[k * 40 + n]) : (short)0;
}

// ---------------- CSR build (dst-sorted) ----------------
__global__ void zero2_kernel(int* __restrict__ deg, int* __restrict__ cur, int N)
{
    int id = blockIdx.x * 256 + threadIdx.x;
    if (id < N) { deg[id] = 0; cur[id] = 0; }
}

__global__ void hist_kernel(const unsigned* __restrict__ eraw, const int* __restrict__ flag,
                            int* __restrict__ deg, int E)
{
    int e = blockIdx.x * 256 + threadIdx.x;
    if (e >= E) return;
    int f = *flag;
    int dst = (int)(f ? eraw[2 * (E + e)] : eraw[E + e]);
    atomicAdd(&deg[dst], 1);
}

__global__ void chunksum_kernel(const int* __restrict__ deg, int* __restrict__ csum, int N)
{
    int b = blockIdx.x, t = threadIdx.x;
    int base = b * CHUNK + t * 4;
    int s = 0;
#pragma unroll
    for (int j = 0; j < 4; ++j) { int i = base + j; if (i < N) s += deg[i]; }
#pragma unroll
    for (int off = 1; off < 64; off <<= 1) s += __shfl_xor(s, off);
    __shared__ int wt[4];
    if ((t & 63) == 0) wt[t >> 6] = s;
    __syncthreads();
    if (t == 0) csum[b] = wt[0] + wt[1] + wt[2] + wt[3];
}

// single wave; NB <= 128
__global__ void chunkscan_kernel(const int* __restrict__ csum, int* __restrict__ coff,
                                 int* __restrict__ rowptrN, int NB, int E)
{
    int lane = threadIdx.x;
    int v0 = (lane < NB) ? csum[lane] : 0;
    int v1 = (lane + 64 < NB) ? csum[lane + 64] : 0;
    int s0 = v0;
#pragma unroll
    for (int off = 1; off < 64; off <<= 1) { int u = __shfl_up(s0, off); if (lane >= off) s0 += u; }
    int tot0 = __shfl(s0, 63);
    if (lane < NB) coff[lane] = s0 - v0;
    int s1 = v1;
#pragma unroll
    for (int off = 1; off < 64; off <<= 1) { int u = __shfl_up(s1, off); if (lane >= off) s1 += u; }
    if (lane + 64 < NB) coff[lane + 64] = tot0 + s1 - v1;
    if (lane == 0) *rowptrN = E;
}

__global__ void writeptr_kernel(const int* __restrict__ deg, const int* __restrict__ coff,
                                int* __restrict__ rowptr, int N)
{
    int b = blockIdx.x, t = threadIdx.x;
    int base = b * CHUNK + t * 4;
    int d[4]; int s = 0;
#pragma unroll
    for (int j = 0; j < 4; ++j) { int i = base + j; d[j] = (i < N) ? deg[i] : 0; s += d[j]; }
    int lane = t & 63, wv = t >> 6;
    int incl = s;
#pragma unroll
    for (int off = 1; off < 64; off <<= 1) { int u = __shfl_up(incl, off); if (lane >= off) incl += u; }
    __shared__ int wt[4];
    if (lane == 63) wt[wv] = incl;
    __syncthreads();
    int wbase = 0;
    for (int w = 0; w < wv; ++w) wbase += wt[w];
    int run = wbase + incl - s + coff[b];
#pragma unroll
    for (int j = 0; j < 4; ++j) { int i = base + j; if (i < N) rowptr[i] = run; run += d[j]; }
}

__global__ void scatter_kernel(const unsigned* __restrict__ eraw, const int* __restrict__ flag,
                               const int* __restrict__ rowptr, int* __restrict__ cur,
                               int* __restrict__ ssorted, int* __restrict__ dsorted, int E)
{
    int e = blockIdx.x * 256 + threadIdx.x;
    if (e >= E) return;
    int f = *flag;
    int src = (int)(f ? eraw[2 * e] : eraw[e]);
    int dst = (int)(f ? eraw[2 * (E + e)] : eraw[E + e]);
    int k = atomicAdd(&cur[dst], 1);
    int pos = rowptr[dst] + k;
    ssorted[pos] = src;
    dsorted[pos] = dst;
}

// ---------------- GEMM1 (MFMA): h1a = x @ W1 rows + interleaved als; ald separate ----
// h1a row layout (stride 80 shorts = 160 B): [0..63] ch bf16, [64..79] = 8 x f32 als.
__global__ __launch_bounds__(256) void gemm1_kernel(
    const float* __restrict__ x, const short* __restrict__ W1Tb,
    const float* __restrict__ as1, const float* __restrict__ ad1,
    short* __restrict__ h1a, float* __restrict__ ald1, int N)
{
    const int l = threadIdx.x & 63, wv = threadIdx.x >> 6;
    const int m = l & 15, g = l >> 4;
    const int arow = blockIdx.x * 64 + wv * 16 + m;    // A-frag row
    const bool rv = arow < N;
    const float* xrow = x + (size_t)arow * 256;

    f32x4 acc[4] = {f32x4{0,0,0,0}, f32x4{0,0,0,0}, f32x4{0,0,0,0}, f32x4{0,0,0,0}};

#pragma unroll
    for (int ks = 0; ks < 8; ++ks) {
        const int k0 = ks * 32 + g * 8;
        float xa[8];
        if (rv) {
            float4 v0 = *(const float4*)(xrow + k0);
            float4 v1 = *(const float4*)(xrow + k0 + 4);
            xa[0] = v0.x; xa[1] = v0.y; xa[2] = v0.z; xa[3] = v0.w;
            xa[4] = v1.x; xa[5] = v1.y; xa[6] = v1.z; xa[7] = v1.w;
        } else {
#pragma unroll
            for (int j = 0; j < 8; ++j) xa[j] = 0.f;
        }
        short8 af;
#pragma unroll
        for (int j = 0; j < 8; ++j) af[j] = bfr(xa[j]);
#pragma unroll
        for (int nt = 0; nt < 4; ++nt) {
            short8 bf_ = *(const short8*)(W1Tb + (size_t)(nt * 16 + m) * 256 + k0);
            acc[nt] = __builtin_amdgcn_mfma_f32_16x16x32_bf16(af, bf_, acc[nt], 0, 0, 0);
        }
    }

    // epilogue: h1a store + per-head attention logits
    const int orow0 = blockIdx.x * 64 + wv * 16 + g * 4;
    float a_sv[4], a_dv[4];
#pragma unroll
    for (int nt = 0; nt < 4; ++nt) { a_sv[nt] = as1[nt * 16 + m]; a_dv[nt] = ad1[nt * 16 + m]; }

    float vs[4][4], vd[4][4];
#pragma unroll
    for (int nt = 0; nt < 4; ++nt)
#pragma unroll
        for (int r = 0; r < 4; ++r) {
            vs[nt][r] = acc[nt][r] * a_sv[nt];
            vd[nt][r] = acc[nt][r] * a_dv[nt];
        }
#pragma unroll
    for (int off = 1; off < 8; off <<= 1)
#pragma unroll
        for (int nt = 0; nt < 4; ++nt)
#pragma unroll
            for (int r = 0; r < 4; ++r) {
                vs[nt][r] += __shfl_xor(vs[nt][r], off);
                vd[nt][r] += __shfl_xor(vd[nt][r], off);
            }

#pragma unroll
    for (int nt = 0; nt < 4; ++nt)
#pragma unroll
        for (int r = 0; r < 4; ++r) {
            int row = orow0 + r;
            if (row < N) h1a[row * 80 + nt * 16 + m] = bfr(acc[nt][r]);
        }
    if ((l & 7) == 0) {
        int par = m >> 3;
#pragma unroll
        for (int nt = 0; nt < 4; ++nt)
#pragma unroll
            for (int r = 0; r < 4; ++r) {
                int row = orow0 + r;
                if (row < N) {
                    ((float*)(h1a + row * 80 + 64))[2 * nt + par] = vs[nt][r];
                    ald1[row * 8 + 2 * nt + par] = vd[nt][r];
                }
            }
    }
}

// ---------------- agg1: per-dst-node softmax + aggregate + bias + ELU ----------------
__global__ __launch_bounds__(256) void agg1_kernel(
    const int* __restrict__ rowptr, const int* __restrict__ srcs,
    const short* __restrict__ h1a, const float* __restrict__ ald1,
    const float* __restrict__ b1, float* __restrict__ x2, int N)
{
    int lane = threadIdx.x & 63, wv = threadIdx.x >> 6;
    int n = blockIdx.x * 4 + wv;
    if (n >= N) return;
    int hb = lane >> 3;
    const short* rown = h1a + n * 80;
    float alsn = ((const float*)(rown + 64))[hb];
    float aldn = ald1[n * 8 + hb];
    float p = __expf(leaky(alsn + aldn));
    float den = p;
    float acc = p * b2f(rown[lane]);
    int beg = rowptr[n], end = rowptr[n + 1];
    int i = beg;
    for (; i + 8 <= end; i += 8) {
        int sv = srcs[i + (lane & 7)];
        int sj[8];
#pragma unroll
        for (int j = 0; j < 8; ++j) sj[j] = __shfl(sv, j);
        float hv[8], av[8];
#pragma unroll
        for (int j = 0; j < 8; ++j) {
            int b80 = sj[j] * 80;
            hv[j] = b2f(h1a[b80 + lane]);
            av[j] = ((const float*)(h1a + b80 + 64))[hb];
        }
#pragma unroll
        for (int j = 0; j < 8; ++j) {
            float pe = __expf(leaky(av[j] + aldn));
            den += pe;
            acc += pe * hv[j];
        }
    }
    if (i < end) {
        int ii = i + (lane & 7);
        int sv = srcs[ii < end ? ii : end - 1];
        int sj[8];
#pragma unroll
        for (int j = 0; j < 8; ++j) sj[j] = __shfl(sv, j);
        float hv[8], av[8];
#pragma unroll
        for (int j = 0; j < 8; ++j) {
            int b80 = sj[j] * 80;
            hv[j] = b2f(h1a[b80 + lane]);
            av[j] = ((const float*)(h1a + b80 + 64))[hb];
        }
#pragma unroll
        for (int j = 0; j < 8; ++j) {
            float pe = (i + j < end) ? __expf(leaky(av[j] + aldn)) : 0.f;
            den += pe;
            acc += pe * hv[j];
        }
    }
    float v = acc / den + b1[lane];
    x2[(size_t)n * 64 + lane] = v > 0.f ? v : expm1f(v);
}

// ---------------- GEMM2 (MFMA): h2a = x2 @ W2 rows; al2s/al2d separate ----------------
__global__ __launch_bounds__(256) void gemm2_kernel(
    const float* __restrict__ x2, const short* __restrict__ W2Tb,
    const float* __restrict__ as2, const float* __restrict__ ad2,
    short* __restrict__ h2a, float* __restrict__ al2s, float* __restrict__ al2d, int N)
{
    const int l = threadIdx.x & 63, wv = threadIdx.x >> 6;
    const int m = l & 15, g = l >> 4;
    const int arow = blockIdx.x * 64 + wv * 16 + m;
    const bool rv = arow < N;
    const float* xrow = x2 + (size_t)arow * 64;

    f32x4 acc[3] = {f32x4{0,0,0,0}, f32x4{0,0,0,0}, f32x4{0,0,0,0}};

#pragma unroll
    for (int ks = 0; ks < 2; ++ks) {
        const int k0 = ks * 32 + g * 8;
        float xa[8];
        if (rv) {
            float4 v0 = *(const float4*)(xrow + k0);
            float4 v1 = *(const float4*)(xrow + k0 + 4);
            xa[0] = v0.x; xa[1] = v0.y; xa[2] = v0.z; xa[3] = v0.w;
            xa[4] = v1.x; xa[5] = v1.y; xa[6] = v1.z; xa[7] = v1.w;
        } else {
#pragma unroll
            for (int j = 0; j < 8; ++j) xa[j] = 0.f;
        }
        short8 af;
#pragma unroll
        for (int j = 0; j < 8; ++j) af[j] = bfr(xa[j]);
#pragma unroll
        for (int nt = 0; nt < 3; ++nt) {
            short8 bf_ = *(const short8*)(W2Tb + (size_t)(nt * 16 + m) * 64 + k0);
            acc[nt] = __builtin_amdgcn_mfma_f32_16x16x32_bf16(af, bf_, acc[nt], 0, 0, 0);
        }
    }

    const int orow0 = blockIdx.x * 64 + wv * 16 + g * 4;
    float a_sv[3], a_dv[3];
#pragma unroll
    for (int nt = 0; nt < 3; ++nt) {
        int c = nt * 16 + m;
        a_sv[nt] = (c < 40) ? as2[c] : 0.f;
        a_dv[nt] = (c < 40) ? ad2[c] : 0.f;
    }
    float vs[4], vd[4];
#pragma unroll
    for (int r = 0; r < 4; ++r) {
        vs[r] = acc[0][r] * a_sv[0] + acc[1][r] * a_sv[1] + acc[2][r] * a_sv[2];
        vd[r] = acc[0][r] * a_dv[0] + acc[1][r] * a_dv[1] + acc[2][r] * a_dv[2];
    }
#pragma unroll
    for (int off = 1; off < 16; off <<= 1)
#pragma unroll
        for (int r = 0; r < 4; ++r) {
            vs[r] += __shfl_xor(vs[r], off);
            vd[r] += __shfl_xor(vd[r], off);
        }

#pragma unroll
    for (int nt = 0; nt < 3; ++nt) {
        int c = nt * 16 + m;
        if (c >= 40) continue;
#pragma unroll
        for (int r = 0; r < 4; ++r) {
            int row = orow0 + r;
            if (row < N) h2a[row * 40 + c] = bfr(acc[nt][r]);
        }
    }
    if (m == 0) {
#pragma unroll
        for (int r = 0; r < 4; ++r) {
            int row = orow0 + r;
            if (row < N) { al2s[row] = vs[r]; al2d[row] = vd[r]; }
        }
    }
}

// ---------------- pe2: per-edge exp(leaky(...)) for layer 2 (edge-parallel) ----------
__global__ void pe2_kernel(const int* __restrict__ ssorted, const int* __restrict__ dsorted,
                           const float* __restrict__ al2s, const float* __restrict__ al2d,
                           float* __restrict__ pe2, int E)
{
    int i = blockIdx.x * 256 + threadIdx.x;
    if (i >= E) return;
    pe2[i] = __expf(leaky(al2s[ssorted[i]] + al2d[dsorted[i]]));
}

// ---------------- agg2: per-dst-node aggregate + bias + log-softmax ----------------
__global__ __launch_bounds__(256) void agg2_kernel(
    const int* __restrict__ rowptr, const int* __restrict__ srcs,
    const float* __restrict__ pe2, const short* __restrict__ h2a,
    const float* __restrict__ al2s, const float* __restrict__ al2d,
    const float* __restrict__ b2, float* __restrict__ out, int N)
{
    int lane = threadIdx.x & 63, wv = threadIdx.x >> 6;
    int n = blockIdx.x * 4 + wv;
    if (n >= N) return;
    bool act = lane < 40;
    float p = __expf(leaky(al2s[n] + al2d[n]));
    float den = p;
    float acc = act ? p * b2f(h2a[n * 40 + lane]) : 0.f;
    int beg = rowptr[n], end = rowptr[n + 1];
    int i = beg;
    for (; i + 8 <= end; i += 8) {
        int q = i + (lane & 7);
        int sv = srcs[q];
        float pv = pe2[q];
        int sj[8]; float pj[8];
#pragma unroll
        for (int j = 0; j < 8; ++j) { sj[j] = __shfl(sv, j); pj[j] = __shfl(pv, j); }
        float hv[8];
#pragma unroll
        for (int j = 0; j < 8; ++j)
            hv[j] = act ? b2f(h2a[sj[j] * 40 + lane]) : 0.f;
#pragma unroll
        for (int j = 0; j < 8; ++j) { den += pj[j]; acc += pj[j] * hv[j]; }
    }
    if (i < end) {
        int ii = i + (lane & 7);
        int q = ii < end ? ii : end - 1;
        int sv = srcs[q];
        float pv = (ii < end) ? pe2[q] : 0.f;
        int sj[8]; float pj[8];
#pragma unroll
        for (int j = 0; j < 8; ++j) { sj[j] = __shfl(sv, j); pj[j] = __shfl(pv, j); }
        float hv[8];
#pragma unroll
        for (int j = 0; j < 8; ++j)
            hv[j] = act ? b2f(h2a[sj[j] * 40 + lane]) : 0.f;
#pragma unroll
        for (int j = 0; j < 8; ++j) { den += pj[j]; acc += pj[j] * hv[j]; }
    }
    float v = act ? acc / den + b2[lane] : -INFINITY;
    float m = v;
#pragma unroll
    for (int off = 1; off < 64; off <<= 1) m = fmaxf(m, __shfl_xor(m, off));
    float e = act ? __expf(v - m) : 0.f;
    float sum = e;
#pragma unroll
    for (int off = 1; off < 64; off <<= 1) sum += __shfl_xor(sum, off);
    if (act) out[(size_t)n * 40 + lane] = v - m - logf(sum);
}

extern "C" void kernel_launch(void* const* d_in, const int* in_sizes, int n_in,
                              void* d_out, int out_size, void* d_ws, size_t ws_size,
                              hipStream_t stream)
{
    const float*    x    = (const float*)d_in[0];
    const unsigned* eraw = (const unsigned*)d_in[1];
    const float*    W1   = (const float*)d_in[2];
    const float*    as1  = (const float*)d_in[3];
    const float*    ad1  = (const float*)d_in[4];
    const float*    b1   = (const float*)d_in[5];
    const float*    W2   = (const float*)d_in[6];
    const float*    as2  = (const float*)d_in[7];
    const float*    ad2  = (const float*)d_in[8];
    const float*    b2   = (const float*)d_in[9];
    float* out = (float*)d_out;

    const int N = in_sizes[0] / 256;
    const int E = in_sizes[1] / 2;
    const int NB = (N + CHUNK - 1) / CHUNK;

    char* ws = (char*)d_ws;
    size_t off = 0;
    auto alloc = [&](size_t bytes) {
        size_t o = off;
        off = (off + bytes + 255) & ~(size_t)255;
        return o;
    };
    int*   ssorted = (int*)  (ws + alloc((size_t)E * 4));
    int*   dsorted = (int*)  (ws + alloc((size_t)E * 4));
    float* pe2     = (float*)(ws + alloc((size_t)E * 4));
    int*   rowptr  = (int*)  (ws + alloc((size_t)(N + 1) * 4));
    int*   deg     = (int*)  (ws + alloc((size_t)N * 4));
    int*   cur     = (int*)  (ws + alloc((size_t)N * 4));
    int*   csum    = (int*)  (ws + alloc((size_t)NB * 4));
    int*   coff    = (int*)  (ws + alloc((size_t)NB * 4));
    int*   flag    = (int*)  (ws + alloc(256));
    short* W1Tb    = (short*)(ws + alloc((size_t)64 * 256 * 2));
    short* W2Tb    = (short*)(ws + alloc((size_t)48 * 64 * 2));
    short* h1a     = (short*)(ws + alloc((size_t)N * 80 * 2));
    short* h2a     = (short*)(ws + alloc((size_t)N * 40 * 2));
    float* ald1    = (float*)(ws + alloc((size_t)N * 8 * 4));
    float* x2      = (float*)(ws + alloc((size_t)N * 64 * 4));
    float* al2s    = (float*)(ws + alloc((size_t)N * 4));
    float* al2d    = (float*)(ws + alloc((size_t)N * 4));

    dim3 B(256);
    detect_kernel<<<1, B, 0, stream>>>(eraw, flag);
    w1t_kernel<<<dim3(64), B, 0, stream>>>(W1, W1Tb);
    w2t_kernel<<<dim3(12), B, 0, stream>>>(W2, W2Tb);

    // CSR build (dst-sorted)
    zero2_kernel<<<dim3((N + 255) / 256), B, 0, stream>>>(deg, cur, N);
    hist_kernel<<<dim3((E + 255) / 256), B, 0, stream>>>(eraw, flag, deg, E);
    chunksum_kernel<<<dim3(NB), B, 0, stream>>>(deg, csum, N);
    chunkscan_kernel<<<1, dim3(64), 0, stream>>>(csum, coff, rowptr + N, NB, E);
    writeptr_kernel<<<dim3(NB), B, 0, stream>>>(deg, coff, rowptr, N);
    scatter_kernel<<<dim3((E + 255) / 256), B, 0, stream>>>(eraw, flag, rowptr, cur,
                                                            ssorted, dsorted, E);

    // layer 1
    gemm1_kernel<<<dim3((N + 63) / 64), B, 0, stream>>>(x, W1Tb, as1, ad1, h1a, ald1, N);
    agg1_kernel<<<dim3((N + 3) / 4), B, 0, stream>>>(rowptr, ssorted, h1a, ald1, b1, x2, N);

    // layer 2
    gemm2_kernel<<<dim3((N + 63) / 64), B, 0, stream>>>(x2, W2Tb, as2, ad2, h2a, al2s, al2d, N);
    pe2_kernel<<<dim3((E + 255) / 256), B, 0, stream>>>(ssorted, dsorted, al2s, al2d, pe2, E);
    agg2_kernel<<<dim3((N + 3) / 4), B, 0, stream>>>(rowptr, ssorted, pe2, h2a,
                                                     al2s, al2d, b2, out, N);
}

// Round 6
// 448.136 us; speedup vs baseline: 2.4689x; 1.0463x over previous
//
#include <hip/hip_runtime.h>
#include <hip/hip_bf16.h>
#include <math.h>

#define NEG_SLOPE 0.2f
#define CHUNK 1024

typedef __attribute__((ext_vector_type(8))) short short8;
typedef __attribute__((ext_vector_type(4))) float f32x4;

__device__ __forceinline__ float leaky(float v) { return v >= 0.f ? v : NEG_SLOPE * v; }

// fp32 -> bf16 RNE (bit trick, finite inputs)
__device__ __forceinline__ short bfr(float f)
{
    union { float f; unsigned u; } v; v.f = f;
    unsigned r = (v.u + 0x7FFFu + ((v.u >> 16) & 1u)) >> 16;
    return (short)r;
}
// bf16 bits -> fp32
__device__ __forceinline__ float b2f(short s)
{
    union { unsigned u; float f; } v; v.u = ((unsigned)(unsigned short)s) << 16;
    return v.f;
}

// fp32 -> OCP e4m3fn (RNE, clamp 448, FTZ-free subnormals)
__device__ __forceinline__ unsigned char enc8(float f)
{
    union { float f; unsigned u; } v; v.f = f;
    unsigned s = (v.u >> 24) & 0x80u;
    v.u &= 0x7FFFFFFFu;
    if (v.f >= 448.f) return (unsigned char)(s | 0x7Eu);       // 448
    if (v.f < 0.015625f) {                                     // subnormal: k * 2^-9
        int mm = (int)rintf(v.f * 512.f);                      // 0..8 (8 carries to 2^-6)
        return (unsigned char)(s | (unsigned)mm);
    }
    unsigned u = v.u + 0x7FFFFu + ((v.u >> 20) & 1u);          // RNE to 3-bit mantissa
    unsigned e = ((u >> 23) & 0xFFu) - 120u;
    unsigned m = (u >> 20) & 7u;
    return (unsigned char)(s | (e << 3) | m);
}

// e4m3fn -> fp32
__device__ __forceinline__ float dec8(unsigned b)
{
#if __has_builtin(__builtin_amdgcn_cvt_f32_fp8)
    return __builtin_amdgcn_cvt_f32_fp8((int)b, 0);
#else
    unsigned s = (b & 0x80u) << 24, em = b & 0x7Fu;
    union { unsigned u; float f; } n; n.u = s | (((em >> 3) + 120u) << 23) | ((em & 7u) << 20);
    union { unsigned u; float f; } t; t.f = (float)em * 0.001953125f; t.u |= s;
    return em >= 8u ? n.f : t.f;
#endif
}

// ---------------- edge dtype detect ----------------
__global__ void detect_kernel(const unsigned* __restrict__ w, int* __restrict__ flag)
{
    __shared__ int anynz;
    if (threadIdx.x == 0) anynz = 0;
    __syncthreads();
    bool nz = false;
#pragma unroll
    for (int j = 0; j < 8; ++j) {
        int idx = 2 * (threadIdx.x + 256 * j) + 1;
        nz |= (w[idx] != 0u);
    }
    if (nz) anynz = 1;
    __syncthreads();
    if (threadIdx.x == 0) *flag = anynz ? 0 : 1;     // 1 => int64 layout
}

// ---------------- weight transpose (bf16) + logit projection vectors ----------------
__global__ void w1t_kernel(const float* __restrict__ W1, short* __restrict__ W1Tb)
{
    int id = blockIdx.x * 256 + threadIdx.x;      // 256*64
    if (id >= 256 * 64) return;
    int k = id >> 6, c = id & 63;
    W1Tb[c * 256 + k] = bfr(W1[id]);
}

// w2a = W2 @ as2, w2d = W2 @ ad2  (64 each); one wave
__global__ void w2ad_kernel(const float* __restrict__ W2, const float* __restrict__ as2,
                            const float* __restrict__ ad2, float* __restrict__ w2a,
                            float* __restrict__ w2d)
{
    int k = threadIdx.x;
    if (k >= 64) return;
    float a = 0.f, d = 0.f;
    for (int c = 0; c < 40; ++c) {
        float w = W2[k * 40 + c];
        a += w * as2[c];
        d += w * ad2[c];
    }
    w2a[k] = a; w2d[k] = d;
}

// ---------------- CSR build (dst-sorted) ----------------
__global__ void zero2_kernel(int* __restrict__ deg, int* __restrict__ cur, int N)
{
    int id = blockIdx.x * 256 + threadIdx.x;
    if (id < N) { deg[id] = 0; cur[id] = 0; }
}

__global__ void hist_kernel(const unsigned* __restrict__ eraw, const int* __restrict__ flag,
                            int* __restrict__ deg, int E)
{
    int e = blockIdx.x * 256 + threadIdx.x;
    if (e >= E) return;
    int f = *flag;
    int dst = (int)(f ? eraw[2 * (E + e)] : eraw[E + e]);
    atomicAdd(&deg[dst], 1);
}

__global__ void chunksum_kernel(const int* __restrict__ deg, int* __restrict__ csum, int N)
{
    int b = blockIdx.x, t = threadIdx.x;
    int base = b * CHUNK + t * 4;
    int s = 0;
#pragma unroll
    for (int j = 0; j < 4; ++j) { int i = base + j; if (i < N) s += deg[i]; }
#pragma unroll
    for (int off = 1; off < 64; off <<= 1) s += __shfl_xor(s, off);
    __shared__ int wt[4];
    if ((t & 63) == 0) wt[t >> 6] = s;
    __syncthreads();
    if (t == 0) csum[b] = wt[0] + wt[1] + wt[2] + wt[3];
}

// single wave; NB <= 128
__global__ void chunkscan_kernel(const int* __restrict__ csum, int* __restrict__ coff,
                                 int* __restrict__ rowptrN, int NB, int E)
{
    int lane = threadIdx.x;
    int v0 = (lane < NB) ? csum[lane] : 0;
    int v1 = (lane + 64 < NB) ? csum[lane + 64] : 0;
    int s0 = v0;
#pragma unroll
    for (int off = 1; off < 64; off <<= 1) { int u = __shfl_up(s0, off); if (lane >= off) s0 += u; }
    int tot0 = __shfl(s0, 63);
    if (lane < NB) coff[lane] = s0 - v0;
    int s1 = v1;
#pragma unroll
    for (int off = 1; off < 64; off <<= 1) { int u = __shfl_up(s1, off); if (lane >= off) s1 += u; }
    if (lane + 64 < NB) coff[lane + 64] = tot0 + s1 - v1;
    if (lane == 0) *rowptrN = E;
}

__global__ void writeptr_kernel(const int* __restrict__ deg, const int* __restrict__ coff,
                                int* __restrict__ rowptr, int N)
{
    int b = blockIdx.x, t = threadIdx.x;
    int base = b * CHUNK + t * 4;
    int d[4]; int s = 0;
#pragma unroll
    for (int j = 0; j < 4; ++j) { int i = base + j; d[j] = (i < N) ? deg[i] : 0; s += d[j]; }
    int lane = t & 63, wv = t >> 6;
    int incl = s;
#pragma unroll
    for (int off = 1; off < 64; off <<= 1) { int u = __shfl_up(incl, off); if (lane >= off) incl += u; }
    __shared__ int wt[4];
    if (lane == 63) wt[wv] = incl;
    __syncthreads();
    int wbase = 0;
    for (int w = 0; w < wv; ++w) wbase += wt[w];
    int run = wbase + incl - s + coff[b];
#pragma unroll
    for (int j = 0; j < 4; ++j) { int i = base + j; if (i < N) rowptr[i] = run; run += d[j]; }
}

__global__ void scatter_kernel(const unsigned* __restrict__ eraw, const int* __restrict__ flag,
                               const int* __restrict__ rowptr, int* __restrict__ cur,
                               int* __restrict__ ssorted, int* __restrict__ dsorted, int E)
{
    int e = blockIdx.x * 256 + threadIdx.x;
    if (e >= E) return;
    int f = *flag;
    int src = (int)(f ? eraw[2 * e] : eraw[e]);
    int dst = (int)(f ? eraw[2 * (E + e)] : eraw[E + e]);
    int k = atomicAdd(&cur[dst], 1);
    int pos = rowptr[dst] + k;
    ssorted[pos] = src;
    dsorted[pos] = dst;
}

// ---------------- GEMM1 (MFMA): h1 = x @ W1 -> fp8 rows + bf16 als + f32 ald ----------
__global__ __launch_bounds__(256) void gemm1_kernel(
    const float* __restrict__ x, const short* __restrict__ W1Tb,
    const float* __restrict__ as1, const float* __restrict__ ad1,
    unsigned char* __restrict__ h1q, short* __restrict__ als1h,
    float* __restrict__ ald1, int N)
{
    const int l = threadIdx.x & 63, wv = threadIdx.x >> 6;
    const int m = l & 15, g = l >> 4;
    const int arow = blockIdx.x * 64 + wv * 16 + m;    // A-frag row
    const bool rv = arow < N;
    const float* xrow = x + (size_t)arow * 256;

    f32x4 acc[4] = {f32x4{0,0,0,0}, f32x4{0,0,0,0}, f32x4{0,0,0,0}, f32x4{0,0,0,0}};

#pragma unroll
    for (int ks = 0; ks < 8; ++ks) {
        const int k0 = ks * 32 + g * 8;
        float xa[8];
        if (rv) {
            float4 v0 = *(const float4*)(xrow + k0);
            float4 v1 = *(const float4*)(xrow + k0 + 4);
            xa[0] = v0.x; xa[1] = v0.y; xa[2] = v0.z; xa[3] = v0.w;
            xa[4] = v1.x; xa[5] = v1.y; xa[6] = v1.z; xa[7] = v1.w;
        } else {
#pragma unroll
            for (int j = 0; j < 8; ++j) xa[j] = 0.f;
        }
        short8 af;
#pragma unroll
        for (int j = 0; j < 8; ++j) af[j] = bfr(xa[j]);
#pragma unroll
        for (int nt = 0; nt < 4; ++nt) {
            short8 bf_ = *(const short8*)(W1Tb + (size_t)(nt * 16 + m) * 256 + k0);
            acc[nt] = __builtin_amdgcn_mfma_f32_16x16x32_bf16(af, bf_, acc[nt], 0, 0, 0);
        }
    }

    // epilogue: fp8 feature store + per-head attention logits
    const int orow0 = blockIdx.x * 64 + wv * 16 + g * 4;
    float a_sv[4], a_dv[4];
#pragma unroll
    for (int nt = 0; nt < 4; ++nt) { a_sv[nt] = as1[nt * 16 + m]; a_dv[nt] = ad1[nt * 16 + m]; }

    float vs[4][4], vd[4][4];
#pragma unroll
    for (int nt = 0; nt < 4; ++nt)
#pragma unroll
        for (int r = 0; r < 4; ++r) {
            vs[nt][r] = acc[nt][r] * a_sv[nt];
            vd[nt][r] = acc[nt][r] * a_dv[nt];
        }
#pragma unroll
    for (int off = 1; off < 8; off <<= 1)
#pragma unroll
        for (int nt = 0; nt < 4; ++nt)
#pragma unroll
            for (int r = 0; r < 4; ++r) {
                vs[nt][r] += __shfl_xor(vs[nt][r], off);
                vd[nt][r] += __shfl_xor(vd[nt][r], off);
            }

#pragma unroll
    for (int nt = 0; nt < 4; ++nt)
#pragma unroll
        for (int r = 0; r < 4; ++r) {
            int row = orow0 + r;
            if (row < N) h1q[row * 64 + nt * 16 + m] = enc8(acc[nt][r]);
        }
    if ((l & 7) == 0) {
        int par = m >> 3;
#pragma unroll
        for (int nt = 0; nt < 4; ++nt)
#pragma unroll
            for (int r = 0; r < 4; ++r) {
                int row = orow0 + r;
                if (row < N) {
                    als1h[row * 8 + 2 * nt + par] = bfr(vs[nt][r]);
                    ald1[row * 8 + 2 * nt + par] = vd[nt][r];
                }
            }
    }
}

// ---------------- agg1: softmax-aggregate + bias + ELU -> xq fp8 + layer2 logits -----
__global__ __launch_bounds__(256) void agg1_kernel(
    const int* __restrict__ rowptr, const int* __restrict__ srcs,
    const unsigned char* __restrict__ h1q, const short* __restrict__ als1h,
    const float* __restrict__ ald1, const float* __restrict__ b1,
    const float* __restrict__ w2a, const float* __restrict__ w2d,
    unsigned char* __restrict__ xq, float* __restrict__ al2s, float* __restrict__ al2d, int N)
{
    int lane = threadIdx.x & 63, wv = threadIdx.x >> 6;
    int n = blockIdx.x * 4 + wv;
    if (n >= N) return;
    int hb = lane >> 3;
    float alsn = b2f(als1h[n * 8 + hb]);
    float aldn = ald1[n * 8 + hb];
    float p = __expf(leaky(alsn + aldn));
    float den = p;
    float acc = p * dec8(h1q[n * 64 + lane]);
    int beg = rowptr[n], end = rowptr[n + 1];
    int i = beg;
    for (; i + 8 <= end; i += 8) {
        int sv = srcs[i + (lane & 7)];
        int sj[8];
#pragma unroll
        for (int j = 0; j < 8; ++j) sj[j] = __shfl(sv, j);
        float hv[8], av[8];
#pragma unroll
        for (int j = 0; j < 8; ++j) {
            hv[j] = dec8(h1q[sj[j] * 64 + lane]);
            av[j] = b2f(als1h[sj[j] * 8 + hb]);
        }
#pragma unroll
        for (int j = 0; j < 8; ++j) {
            float pe = __expf(leaky(av[j] + aldn));
            den += pe;
            acc += pe * hv[j];
        }
    }
    if (i < end) {
        int ii = i + (lane & 7);
        int sv = srcs[ii < end ? ii : end - 1];
        int sj[8];
#pragma unroll
        for (int j = 0; j < 8; ++j) sj[j] = __shfl(sv, j);
        float hv[8], av[8];
#pragma unroll
        for (int j = 0; j < 8; ++j) {
            hv[j] = dec8(h1q[sj[j] * 64 + lane]);
            av[j] = b2f(als1h[sj[j] * 8 + hb]);
        }
#pragma unroll
        for (int j = 0; j < 8; ++j) {
            float pe = (i + j < end) ? __expf(leaky(av[j] + aldn)) : 0.f;
            den += pe;
            acc += pe * hv[j];
        }
    }
    float v = acc / den + b1[lane];
    float xv = v > 0.f ? v : expm1f(v);
    xq[n * 64 + lane] = enc8(xv);
    // layer-2 logits from exact xv: al2s = x2 . (W2 as2), al2d = x2 . (W2 ad2)
    float sa = xv * w2a[lane], sd = xv * w2d[lane];
#pragma unroll
    for (int off = 1; off < 64; off <<= 1) {
        sa += __shfl_xor(sa, off);
        sd += __shfl_xor(sd, off);
    }
    if (lane == 0) { al2s[n] = sa; al2d[n] = sd; }
}

// ---------------- pe2: per-edge exp(leaky(...)) for layer 2 (edge-parallel) ----------
__global__ void pe2_kernel(const int* __restrict__ ssorted, const int* __restrict__ dsorted,
                           const float* __restrict__ al2s, const float* __restrict__ al2d,
                           float* __restrict__ pe2, int E)
{
    int i = blockIdx.x * 256 + threadIdx.x;
    if (i >= E) return;
    pe2[i] = __expf(leaky(al2s[ssorted[i]] + al2d[dsorted[i]]));
}

// ---------------- agg2: aggregate x2 (fp8) then project W2 + bias + log-softmax ------
__global__ __launch_bounds__(256) void agg2_kernel(
    const int* __restrict__ rowptr, const int* __restrict__ srcs,
    const float* __restrict__ pe2, const unsigned char* __restrict__ xq,
    const float* __restrict__ al2s, const float* __restrict__ al2d,
    const float* __restrict__ W2, const float* __restrict__ b2,
    float* __restrict__ out, int N)
{
    __shared__ float W2s[64][40];
    __shared__ float gx[4][64];
    int t = threadIdx.x;
    for (int id = t; id < 64 * 40; id += 256) W2s[id / 40][id % 40] = W2[id];
    __syncthreads();

    int lane = t & 63, wv = t >> 6;
    int n = blockIdx.x * 4 + wv;
    if (n >= N) return;
    float p = __expf(leaky(al2s[n] + al2d[n]));
    float den = p;
    float g = p * dec8(xq[n * 64 + lane]);
    int beg = rowptr[n], end = rowptr[n + 1];
    int i = beg;
    for (; i + 8 <= end; i += 8) {
        int q = i + (lane & 7);
        int sv = srcs[q];
        float pv = pe2[q];
        int sj[8]; float pj[8];
#pragma unroll
        for (int j = 0; j < 8; ++j) { sj[j] = __shfl(sv, j); pj[j] = __shfl(pv, j); }
        float hv[8];
#pragma unroll
        for (int j = 0; j < 8; ++j) hv[j] = dec8(xq[sj[j] * 64 + lane]);
#pragma unroll
        for (int j = 0; j < 8; ++j) { den += pj[j]; g += pj[j] * hv[j]; }
    }
    if (i < end) {
        int ii = i + (lane & 7);
        int q = ii < end ? ii : end - 1;
        int sv = srcs[q];
        float pv = (ii < end) ? pe2[q] : 0.f;
        int sj[8]; float pj[8];
#pragma unroll
        for (int j = 0; j < 8; ++j) { sj[j] = __shfl(sv, j); pj[j] = __shfl(pv, j); }
        float hv[8];
#pragma unroll
        for (int j = 0; j < 8; ++j) hv[j] = dec8(xq[sj[j] * 64 + lane]);
#pragma unroll
        for (int j = 0; j < 8; ++j) { den += pj[j]; g += pj[j] * hv[j]; }
    }
    g /= den;
    gx[wv][lane] = g;            // same-wave LDS handoff (ordered within wave)

    bool act = lane < 40;
    float outv = 0.f;
    if (act) {
#pragma unroll 8
        for (int k = 0; k < 64; ++k) outv += gx[wv][k] * W2s[k][lane];
        outv += b2[lane];
    }
    float vv = act ? outv : -INFINITY;
    float m = vv;
#pragma unroll
    for (int off = 1; off < 64; off <<= 1) m = fmaxf(m, __shfl_xor(m, off));
    float e = act ? __expf(vv - m) : 0.f;
    float sum = e;
#pragma unroll
    for (int off = 1; off < 64; off <<= 1) sum += __shfl_xor(sum, off);
    if (act) out[(size_t)n * 40 + lane] = vv - m - logf(sum);
}

extern "C" void kernel_launch(void* const* d_in, const int* in_sizes, int n_in,
                              void* d_out, int out_size, void* d_ws, size_t ws_size,
                              hipStream_t stream)
{
    const float*    x    = (const float*)d_in[0];
    const unsigned* eraw = (const unsigned*)d_in[1];
    const float*    W1   = (const float*)d_in[2];
    const float*    as1  = (const float*)d_in[3];
    const float*    ad1  = (const float*)d_in[4];
    const float*    b1   = (const float*)d_in[5];
    const float*    W2   = (const float*)d_in[6];
    const float*    as2  = (const float*)d_in[7];
    const float*    ad2  = (const float*)d_in[8];
    const float*    b2   = (const float*)d_in[9];
    float* out = (float*)d_out;

    const int N = in_sizes[0] / 256;
    const int E = in_sizes[1] / 2;
    const int NB = (N + CHUNK - 1) / CHUNK;

    char* ws = (char*)d_ws;
    size_t off = 0;
    auto alloc = [&](size_t bytes) {
        size_t o = off;
        off = (off + bytes + 255) & ~(size_t)255;
        return o;
    };
    int*   ssorted = (int*)  (ws + alloc((size_t)E * 4));
    int*   dsorted = (int*)  (ws + alloc((size_t)E * 4));
    float* pe2     = (float*)(ws + alloc((size_t)E * 4));
    int*   rowptr  = (int*)  (ws + alloc((size_t)(N + 1) * 4));
    int*   deg     = (int*)  (ws + alloc((size_t)N * 4));
    int*   cur     = (int*)  (ws + alloc((size_t)N * 4));
    int*   csum    = (int*)  (ws + alloc((size_t)NB * 4));
    int*   coff    = (int*)  (ws + alloc((size_t)NB * 4));
    int*   flag    = (int*)  (ws + alloc(256));
    short* W1Tb    = (short*)(ws + alloc((size_t)64 * 256 * 2));
    unsigned char* h1q = (unsigned char*)(ws + alloc((size_t)N * 64));
    unsigned char* xq  = (unsigned char*)(ws + alloc((size_t)N * 64));
    short* als1h   = (short*)(ws + alloc((size_t)N * 8 * 2));
    float* ald1    = (float*)(ws + alloc((size_t)N * 8 * 4));
    float* al2s    = (float*)(ws + alloc((size_t)N * 4));
    float* al2d    = (float*)(ws + alloc((size_t)N * 4));
    float* w2a     = (float*)(ws + alloc(64 * 4));
    float* w2d     = (float*)(ws + alloc(64 * 4));

    dim3 B(256);
    detect_kernel<<<1, B, 0, stream>>>(eraw, flag);
    w1t_kernel<<<dim3(64), B, 0, stream>>>(W1, W1Tb);
    w2ad_kernel<<<1, dim3(64), 0, stream>>>(W2, as2, ad2, w2a, w2d);

    // CSR build (dst-sorted)
    zero2_kernel<<<dim3((N + 255) / 256), B, 0, stream>>>(deg, cur, N);
    hist_kernel<<<dim3((E + 255) / 256), B, 0, stream>>>(eraw, flag, deg, E);
    chunksum_kernel<<<dim3(NB), B, 0, stream>>>(deg, csum, N);
    chunkscan_kernel<<<1, dim3(64), 0, stream>>>(csum, coff, rowptr + N, NB, E);
    writeptr_kernel<<<dim3(NB), B, 0, stream>>>(deg, coff, rowptr, N);
    scatter_kernel<<<dim3((E + 255) / 256), B, 0, stream>>>(eraw, flag, rowptr, cur,
                                                            ssorted, dsorted, E);

    // layer 1
    gemm1_kernel<<<dim3((N + 63) / 64), B, 0, stream>>>(x, W1Tb, as1, ad1, h1q, als1h, ald1, N);
    agg1_kernel<<<dim3((N + 3) / 4), B, 0, stream>>>(rowptr, ssorted, h1q, als1h, ald1,
                                                     b1, w2a, w2d, xq, al2s, al2d, N);

    // layer 2 (gemm2 folded away: aggregate fp8 x2, then project by W2 in epilogue)
    pe2_kernel<<<dim3((E + 255) / 256), B, 0, stream>>>(ssorted, dsorted, al2s, al2d, pe2, E);
    agg2_kernel<<<dim3((N + 3) / 4), B, 0, stream>>>(rowptr, ssorted, pe2, xq,
                                                     al2s, al2d, W2, b2, out, N);
}